// Round 8
// baseline (807.212 us; speedup 1.0000x reference)
//
#include <hip/hip_runtime.h>

#define D0 232
#define MED 1024
#define HID 256
#define TDIM 768
#define NTRAIN 4096
#define NBLK 512
#define NTHR 256

typedef short bf16x8 __attribute__((ext_vector_type(8)));
typedef float f32x4  __attribute__((ext_vector_type(4)));
typedef unsigned short u16;

__device__ __forceinline__ u16 f2bf(float f) {
    unsigned u = __float_as_uint(f);
    return (u16)((u + 0x7FFFu + ((u >> 16) & 1u)) >> 16);
}
__device__ __forceinline__ float bf2f(u16 h) {
    return __uint_as_float(((unsigned)h) << 16);
}
__device__ __forceinline__ void cvt8(const float4& a0, const float4& a1,
                                     bf16x8& h, bf16x8& l) {
    float f[8] = {a0.x, a0.y, a0.z, a0.w, a1.x, a1.y, a1.z, a1.w};
    #pragma unroll
    for (int i = 0; i < 8; ++i) {
        u16 hh = f2bf(f[i]);
        h[i] = (short)hh;
        l[i] = (short)f2bf(f[i] - bf2f(hh));
    }
}
__device__ __forceinline__ void cvt4(const float4 v, ushort4& h, ushort4& l) {
    h.x = f2bf(v.x); l.x = f2bf(v.x - bf2f(h.x));
    h.y = f2bf(v.y); l.y = f2bf(v.y - bf2f(h.y));
    h.z = f2bf(v.z); l.z = f2bf(v.z - bf2f(h.z));
    h.w = f2bf(v.w); l.w = f2bf(v.w - bf2f(h.w));
}

#define SROW(r, k) ((((r) ^ (k)) & 7) | ((r) & ~7))

struct Params {
    const float *P, *bp, *b1, *b2, *Q, *bt, *clsW, *clsb;
    const float *cWp, *cW1l, *cW1r, *cW2l, *cW2r, *cWt;   // fp32 weight sources
    const int *srcE, *dstE, *mids, *pids;
    int E, B;
    float *x0f, *h1f, *x2f, *invdeg, *out;
    u16 *x0h, *x0l, *h1h, *h1l, *agh, *agl;
    u16 *Wph, *Wpl, *W1lh, *W1ll, *W1rh, *W1rl, *W2lh, *W2ll, *W2rh, *W2rl, *Wth, *Wtl;
    int *hist, *cursor, *row_ptr, *csr;
    unsigned *bar;          // [0]=count, [1]=generation (zeroed by memset each launch)
};

// ---- device-scope generational grid barrier (all NBLK blocks co-resident) ----
__device__ __forceinline__ void gridbar(unsigned* bar)
{
    __syncthreads();
    if (threadIdx.x == 0) {
        __threadfence();
        unsigned g = __hip_atomic_load(&bar[1], __ATOMIC_ACQUIRE, __HIP_MEMORY_SCOPE_AGENT);
        unsigned old = __hip_atomic_fetch_add(&bar[0], 1u, __ATOMIC_ACQ_REL, __HIP_MEMORY_SCOPE_AGENT);
        if (old == (unsigned)NBLK - 1u) {
            __hip_atomic_store(&bar[0], 0u, __ATOMIC_RELAXED, __HIP_MEMORY_SCOPE_AGENT);
            __hip_atomic_fetch_add(&bar[1], 1u, __ATOMIC_ACQ_REL, __HIP_MEMORY_SCOPE_AGENT);
        } else {
            while (__hip_atomic_load(&bar[1], __ATOMIC_ACQUIRE, __HIP_MEMORY_SCOPE_AGENT) == g)
                __builtin_amdgcn_s_sleep(4);
        }
        __threadfence();
    }
    __syncthreads();
}

// ---- node GEMM phase: tile 32x64, 512 tiles = gridDim, wave = 16 cols ----
template<int CONVA, int RELU, int EMIT, int NPASS>
__device__ __forceinline__ void gemm_phase(
    short* sAh, short* sAl,
    const float* A1f, const u16* A1h, const u16* A1l,
    const u16* B1h, const u16* B1l,
    const u16* A2h, const u16* A2l,
    const u16* B2h, const u16* B2l,
    const float* bias,
    float* Cf, u16* Chi, u16* Clo,
    int N, int K)
{
    const int tid  = threadIdx.x;
    const int bid  = blockIdx.x;
    const int lane = tid & 63;
    const int wn   = tid >> 6;
    const int l15  = lane & 15;
    const int l4   = lane >> 4;
    const int row0 = (bid >> 2) * 32;
    const int col0 = (bid & 3) * 64;

    const int aRow  = tid >> 3;        // 0..31
    const int aKc   = tid & 7;
    const int aSlot = (aKc * 32 + SROW(aRow, aKc)) * 8;

    const int  colW  = col0 + wn * 16 + l15;
    const bool colOk = colW < N;
    const size_t wBase = (size_t)(colOk ? colW : 0) * K;

    const bf16x8 Z8 = {0, 0, 0, 0, 0, 0, 0, 0};
    f32x4 acc[2];
    acc[0] = (f32x4){0.f, 0.f, 0.f, 0.f};
    acc[1] = (f32x4){0.f, 0.f, 0.f, 0.f};

    for (int pass = 0; pass < NPASS; ++pass) {
        const u16* Bh = pass ? B2h : B1h;
        const u16* Bl = pass ? B2l : B1l;
        const u16* Ah = pass ? A2h : A1h;
        const u16* Al = pass ? A2l : A1l;
        const size_t aOff = (size_t)(row0 + aRow) * K;

        float4 qa0, qa1;
        bf16x8 ph, pl;

        auto loadA = [&](int k0) {
            int gk = k0 + aKc * 8;
            bool v = gk < K;
            if (CONVA && pass == 0) {
                qa0 = v ? *(const float4*)(A1f + aOff + gk)     : make_float4(0.f, 0.f, 0.f, 0.f);
                qa1 = v ? *(const float4*)(A1f + aOff + gk + 4) : make_float4(0.f, 0.f, 0.f, 0.f);
            } else {
                ph = v ? *(const bf16x8*)(Ah + aOff + gk) : Z8;
                pl = v ? *(const bf16x8*)(Al + aOff + gk) : Z8;
            }
        };

        loadA(0);
        for (int k0 = 0; k0 < K; k0 += 64) {
            bf16x8 bh[2], bl[2];
            #pragma unroll
            for (int ks = 0; ks < 2; ++ks) {
                int kb = k0 + (ks * 4 + l4) * 8;
                bool v = colOk && kb < K;
                bh[ks] = v ? *(const bf16x8*)(Bh + wBase + kb) : Z8;
                bl[ks] = v ? *(const bf16x8*)(Bl + wBase + kb) : Z8;
            }
            if (CONVA && pass == 0) {
                bf16x8 h, l; cvt8(qa0, qa1, h, l);
                *(bf16x8*)(sAh + aSlot) = h;
                *(bf16x8*)(sAl + aSlot) = l;
            } else {
                *(bf16x8*)(sAh + aSlot) = ph;
                *(bf16x8*)(sAl + aSlot) = pl;
            }
            __syncthreads();
            if (k0 + 64 < K) loadA(k0 + 64);

            #pragma unroll
            for (int ks = 0; ks < 2; ++ks) {
                const int pb = ks * 4 + l4;
                bf16x8 ah[2], al[2];
                #pragma unroll
                for (int m = 0; m < 2; ++m) {
                    int sl = (pb * 32 + SROW(m * 16 + l15, pb)) * 8;
                    ah[m] = *(const bf16x8*)(sAh + sl);
                    al[m] = *(const bf16x8*)(sAl + sl);
                }
                #pragma unroll
                for (int m = 0; m < 2; ++m)
                    acc[m] = __builtin_amdgcn_mfma_f32_16x16x32_bf16(ah[m], bh[ks], acc[m], 0, 0, 0);
                #pragma unroll
                for (int m = 0; m < 2; ++m)
                    acc[m] = __builtin_amdgcn_mfma_f32_16x16x32_bf16(ah[m], bl[ks], acc[m], 0, 0, 0);
                #pragma unroll
                for (int m = 0; m < 2; ++m)
                    acc[m] = __builtin_amdgcn_mfma_f32_16x16x32_bf16(al[m], bh[ks], acc[m], 0, 0, 0);
            }
            __syncthreads();
        }
    }

    if (colOk) {
        const float bv = bias[colW];
        #pragma unroll
        for (int m = 0; m < 2; ++m) {
            #pragma unroll
            for (int r = 0; r < 4; ++r) {
                int row = row0 + m * 16 + l4 * 4 + r;
                float v = acc[m][r] + bv;
                if (RELU) v = fmaxf(v, 0.0f);
                size_t idx = (size_t)row * N + colW;
                Cf[idx] = v;
                if (EMIT) {
                    u16 h = f2bf(v);
                    Chi[idx] = h;
                    Clo[idx] = f2bf(v - bf2f(h));
                }
            }
        }
    }
}

// ---- aggregation phase: one wave per node (2 nodes/wave) ----
__device__ __forceinline__ void agg_phase(
    const int* row_ptr, const int* csr, const float* invdeg,
    const float* x, u16* agh, u16* agl, int D)
{
    const int gw   = blockIdx.x * 4 + (threadIdx.x >> 6);
    const int lane = threadIdx.x & 63;
    const bool act = lane < (D >> 2);
    const int fo = lane * 4;

    for (int node = gw; node < NTRAIN; node += NBLK * 4) {
        const int beg = row_ptr[node], end = row_ptr[node + 1];
        float4 s0 = {0,0,0,0}, s1 = {0,0,0,0}, s2 = {0,0,0,0}, s3 = {0,0,0,0};
        int j = beg;
        for (; j + 3 < end; j += 4) {
            int n0 = csr[j], n1 = csr[j+1], n2 = csr[j+2], n3 = csr[j+3];
            if (act) {
                float4 v0 = *(const float4*)(&x[(size_t)n0 * D + fo]);
                float4 v1 = *(const float4*)(&x[(size_t)n1 * D + fo]);
                float4 v2 = *(const float4*)(&x[(size_t)n2 * D + fo]);
                float4 v3 = *(const float4*)(&x[(size_t)n3 * D + fo]);
                s0.x += v0.x; s0.y += v0.y; s0.z += v0.z; s0.w += v0.w;
                s1.x += v1.x; s1.y += v1.y; s1.z += v1.z; s1.w += v1.w;
                s2.x += v2.x; s2.y += v2.y; s2.z += v2.z; s2.w += v2.w;
                s3.x += v3.x; s3.y += v3.y; s3.z += v3.z; s3.w += v3.w;
            }
        }
        for (; j < end; ++j) {
            int n = csr[j];
            if (act) {
                float4 v = *(const float4*)(&x[(size_t)n * D + fo]);
                s0.x += v.x; s0.y += v.y; s0.z += v.z; s0.w += v.w;
            }
        }
        if (act) {
            const float inv = invdeg[node];
            float4 r;
            r.x = (s0.x + s1.x + s2.x + s3.x) * inv;
            r.y = (s0.y + s1.y + s2.y + s3.y) * inv;
            r.z = (s0.z + s1.z + s2.z + s3.z) * inv;
            r.w = (s0.w + s1.w + s2.w + s3.w) * inv;
            ushort4 h, l; cvt4(r, h, l);
            *(ushort4*)(&agh[(size_t)node * D + fo]) = h;
            *(ushort4*)(&agl[(size_t)node * D + fo]) = l;
        }
    }
}

// ---- fused q-GEMM + head phase: tile 32 rows, 4 waves x 64 cols ----
__device__ __forceinline__ void qhead_phase(const Params& p, short* sAh, short* sAl, float* hacc)
{
    const int tid  = threadIdx.x;
    const int lane = tid & 63;
    const int wn   = tid >> 6;
    const int l15  = lane & 15;
    const int l4   = lane >> 4;
    constexpr int K = TDIM, N = D0;

    for (int tile = blockIdx.x; tile * 32 < p.B; tile += NBLK) {
        const int row0 = tile * 32;
        const int r  = tid >> 3;
        const int kc = tid & 7;
        const int slot = (kc * 32 + SROW(r, kc)) * 8;
        const size_t ab = (size_t)p.pids[row0 + r] * K;

        int colW[4]; bool cOk[4]; size_t wB[4];
        #pragma unroll
        for (int j = 0; j < 4; ++j) {
            colW[j] = wn * 64 + j * 16 + l15;
            cOk[j]  = colW[j] < N;
            wB[j]   = (size_t)(cOk[j] ? colW[j] : 0) * K;
        }

        const bf16x8 Z8 = {0, 0, 0, 0, 0, 0, 0, 0};
        f32x4 acc[2][4];
        #pragma unroll
        for (int m = 0; m < 2; ++m)
            #pragma unroll
            for (int j = 0; j < 4; ++j)
                acc[m][j] = (f32x4){0.f, 0.f, 0.f, 0.f};

        float4 qa0, qa1;
        auto loadA = [&](int k0) {
            qa0 = *(const float4*)(p.Q + ab + k0 + kc * 8);
            qa1 = *(const float4*)(p.Q + ab + k0 + kc * 8 + 4);
        };

        loadA(0);
        for (int k0 = 0; k0 < K; k0 += 64) {
            bf16x8 bh[2][4], bl[2][4];
            #pragma unroll
            for (int ks = 0; ks < 2; ++ks) {
                int kb = k0 + (ks * 4 + l4) * 8;
                #pragma unroll
                for (int j = 0; j < 4; ++j) {
                    bh[ks][j] = cOk[j] ? *(const bf16x8*)(p.Wth + wB[j] + kb) : Z8;
                    bl[ks][j] = cOk[j] ? *(const bf16x8*)(p.Wtl + wB[j] + kb) : Z8;
                }
            }
            {
                bf16x8 h, l; cvt8(qa0, qa1, h, l);
                *(bf16x8*)(sAh + slot) = h;
                *(bf16x8*)(sAl + slot) = l;
            }
            __syncthreads();
            if (k0 + 64 < K) loadA(k0 + 64);

            #pragma unroll
            for (int ks = 0; ks < 2; ++ks) {
                const int pb = ks * 4 + l4;
                bf16x8 ah[2], al[2];
                #pragma unroll
                for (int m = 0; m < 2; ++m) {
                    int sl = (pb * 32 + SROW(m * 16 + l15, pb)) * 8;
                    ah[m] = *(const bf16x8*)(sAh + sl);
                    al[m] = *(const bf16x8*)(sAl + sl);
                }
                #pragma unroll
                for (int m = 0; m < 2; ++m)
                    #pragma unroll
                    for (int j = 0; j < 4; ++j)
                        acc[m][j] = __builtin_amdgcn_mfma_f32_16x16x32_bf16(ah[m], bh[ks][j], acc[m][j], 0, 0, 0);
                #pragma unroll
                for (int m = 0; m < 2; ++m)
                    #pragma unroll
                    for (int j = 0; j < 4; ++j)
                        acc[m][j] = __builtin_amdgcn_mfma_f32_16x16x32_bf16(ah[m], bl[ks][j], acc[m][j], 0, 0, 0);
                #pragma unroll
                for (int m = 0; m < 2; ++m)
                    #pragma unroll
                    for (int j = 0; j < 4; ++j)
                        acc[m][j] = __builtin_amdgcn_mfma_f32_16x16x32_bf16(al[m], bh[ks][j], acc[m][j], 0, 0, 0);
            }
            __syncthreads();
        }

        // head: out = ((q + bias) * x2[mid]) @ clsW^T + clsb
        if (tid < 64) hacc[tid] = 0.f;
        __syncthreads();

        float bv[4], w0[4], w1[4];
        #pragma unroll
        for (int j = 0; j < 4; ++j) {
            bv[j] = cOk[j] ? p.bt[colW[j]]       : 0.f;
            w0[j] = cOk[j] ? p.clsW[colW[j]]     : 0.f;
            w1[j] = cOk[j] ? p.clsW[N + colW[j]] : 0.f;
        }

        float s0[2][4] = {}, s1[2][4] = {};
        #pragma unroll
        for (int m = 0; m < 2; ++m) {
            #pragma unroll
            for (int rr = 0; rr < 4; ++rr) {
                const int mid = p.mids[row0 + m * 16 + l4 * 4 + rr];
                const float* xr = p.x2f + (size_t)mid * N;
                #pragma unroll
                for (int j = 0; j < 4; ++j) {
                    if (cOk[j]) {
                        float pv = (acc[m][j][rr] + bv[j]) * xr[colW[j]];
                        s0[m][rr] += pv * w0[j];
                        s1[m][rr] += pv * w1[j];
                    }
                }
            }
        }
        #pragma unroll
        for (int off = 1; off < 16; off <<= 1)
            #pragma unroll
            for (int m = 0; m < 2; ++m)
                #pragma unroll
                for (int rr = 0; rr < 4; ++rr) {
                    s0[m][rr] += __shfl_xor(s0[m][rr], off);
                    s1[m][rr] += __shfl_xor(s1[m][rr], off);
                }
        if (l15 == 0) {
            #pragma unroll
            for (int m = 0; m < 2; ++m)
                #pragma unroll
                for (int rr = 0; rr < 4; ++rr) {
                    int lr = m * 16 + l4 * 4 + rr;
                    atomicAdd(&hacc[lr * 2 + 0], s0[m][rr]);
                    atomicAdd(&hacc[lr * 2 + 1], s1[m][rr]);
                }
        }
        __syncthreads();
        if (tid < 64) {
            int rr = tid >> 1, c = tid & 1;
            p.out[(size_t)(row0 + rr) * 2 + c] = hacc[tid] + p.clsb[c];
        }
        __syncthreads();
    }
}

// ---- the single persistent kernel ----
__global__ __launch_bounds__(NTHR, 2) void mega(Params p)
{
    __shared__ short sAh[2048], sAl[2048];
    __shared__ int   s_scan[256];
    __shared__ float hacc[64];

    const int tid  = threadIdx.x;
    const int bid  = blockIdx.x;
    const int gidx = bid * NTHR + tid;

    // ---- P1: edge histogram + weight fp32 -> hi/lo plane conversion ----
    for (int e = gidx; e < p.E; e += NBLK * NTHR)
        atomicAdd(&p.hist[p.dstE[e]], 1);

    auto convseg = [&](const float* s, u16* h, u16* l, int n4) {
        for (int i = gidx; i < n4; i += NBLK * NTHR) {
            float4 v = ((const float4*)s)[i];
            ushort4 hh, ll; cvt4(v, hh, ll);
            ((ushort4*)h)[i] = hh;
            ((ushort4*)l)[i] = ll;
        }
    };
    convseg(p.cWp,  p.Wph,  p.Wpl,  (D0 * MED) / 4);
    convseg(p.cW1l, p.W1lh, p.W1ll, (HID * D0) / 4);
    convseg(p.cW1r, p.W1rh, p.W1rl, (HID * D0) / 4);
    convseg(p.cW2l, p.W2lh, p.W2ll, (HID * D0) / 4);
    convseg(p.cW2r, p.W2rh, p.W2rl, (HID * D0) / 4);
    convseg(p.cWt,  p.Wth,  p.Wtl,  (D0 * TDIM) / 4);
    gridbar(p.bar);

    // ---- P2: exclusive scan of degrees (block 0), invdeg, zero cursors ----
    if (bid == 0) {
        const int base = tid * 16;
        int v[16]; int s = 0;
        #pragma unroll
        for (int i = 0; i < 16; ++i) { v[i] = p.hist[base + i]; s += v[i]; }
        s_scan[tid] = s;
        __syncthreads();
        for (int off = 1; off < 256; off <<= 1) {
            int t = (tid >= off) ? s_scan[tid - off] : 0;
            __syncthreads();
            s_scan[tid] += t;
            __syncthreads();
        }
        int run = s_scan[tid] - s;
        #pragma unroll
        for (int i = 0; i < 16; ++i) {
            p.row_ptr[base + i] = run;
            p.invdeg[base + i]  = 1.0f / fmaxf((float)v[i], 1.0f);
            p.cursor[base + i]  = 0;
            run += v[i];
        }
        if (tid == 255) p.row_ptr[4096] = p.E;
    }
    gridbar(p.bar);

    // ---- P3: CSR scatter + x0 = P @ Wp^T + b (emits planes) ----
    for (int e = gidx; e < p.E; e += NBLK * NTHR) {
        int d = p.dstE[e];
        int pos = atomicAdd(&p.cursor[d], 1);
        p.csr[p.row_ptr[d] + pos] = p.srcE[e];
    }
    gemm_phase<1, 0, 1, 1>(sAh, sAl,
        p.P, nullptr, nullptr, p.Wph, p.Wpl,
        nullptr, nullptr, nullptr, nullptr,
        p.bp, p.x0f, p.x0h, p.x0l, D0, MED);
    gridbar(p.bar);

    // ---- P4: layer-1 aggregation ----
    agg_phase(p.row_ptr, p.csr, p.invdeg, p.x0f, p.agh, p.agl, D0);
    gridbar(p.bar);

    // ---- P5: h1 = relu(agg @ W1l^T + b1 + x0 @ W1r^T) (emits planes) ----
    gemm_phase<0, 1, 1, 2>(sAh, sAl,
        nullptr, p.agh, p.agl, p.W1lh, p.W1ll,
        p.x0h, p.x0l, p.W1rh, p.W1rl,
        p.b1, p.h1f, p.h1h, p.h1l, HID, D0);
    gridbar(p.bar);

    // ---- P6: layer-2 aggregation ----
    agg_phase(p.row_ptr, p.csr, p.invdeg, p.h1f, p.agh, p.agl, HID);
    gridbar(p.bar);

    // ---- P7: x2 = agg @ W2l^T + b2 + h1 @ W2r^T ----
    gemm_phase<0, 0, 0, 2>(sAh, sAl,
        nullptr, p.agh, p.agl, p.W2lh, p.W2ll,
        p.h1h, p.h1l, p.W2rh, p.W2rl,
        p.b2, p.x2f, nullptr, nullptr, D0, HID);
    gridbar(p.bar);

    // ---- P8: fused q-GEMM + head -> d_out ----
    qhead_phase(p, sAh, sAl, hacc);
}

extern "C" void kernel_launch(void* const* d_in, const int* in_sizes, int n_in,
                              void* d_out, int out_size, void* d_ws, size_t ws_size,
                              hipStream_t stream)
{
    const float* P_weight     = (const float*)d_in[0];
    const float* model_proj_W = (const float*)d_in[1];
    const float* model_proj_b = (const float*)d_in[2];
    const float* sage1_Wl     = (const float*)d_in[3];
    const float* sage1_bl     = (const float*)d_in[4];
    const float* sage1_Wr     = (const float*)d_in[5];
    const float* sage2_Wl     = (const float*)d_in[6];
    const float* sage2_bl     = (const float*)d_in[7];
    const float* sage2_Wr     = (const float*)d_in[8];
    const float* Q_weight     = (const float*)d_in[9];
    const float* text_proj_W  = (const float*)d_in[10];
    const float* text_proj_b  = (const float*)d_in[11];
    const float* cls_W        = (const float*)d_in[12];
    const float* cls_b        = (const float*)d_in[13];
    const int*   edge_index   = (const int*)d_in[14];
    const int*   model_ids    = (const int*)d_in[15];
    const int*   prompt_ids   = (const int*)d_in[16];

    const int E = in_sizes[14] / 2;
    const int B = in_sizes[15];

    // ---- workspace layout ----
    const size_t nX0 = (size_t)NTRAIN * D0;
    const size_t nH1 = (size_t)NTRAIN * HID;
    const size_t nWp = (size_t)D0 * MED;
    const size_t nWs = (size_t)HID * D0;
    const size_t nWt = (size_t)D0 * TDIM;
    const size_t nWAll = nWp + 4 * nWs + nWt;

    float* fp  = (float*)d_ws;
    float* x0f = fp;  fp += nX0;
    float* h1f = fp;  fp += nH1;
    float* x2f = fp;  fp += nX0;
    u16* sp  = (u16*)fp;
    u16* x0h = sp;    sp += nX0;
    u16* x0l = sp;    sp += nX0;
    u16* h1h = sp;    sp += nH1;
    u16* h1l = sp;    sp += nH1;
    u16* agh = sp;    sp += nH1;
    u16* agl = sp;    sp += nH1;
    u16* Wh  = sp;    sp += nWAll;
    u16* Wl  = sp;    sp += nWAll;
    int* ib  = (int*)sp;
    int*      hist    = ib;                      // 4096
    unsigned* bar     = (unsigned*)(ib + 4096);  // 2 (+pad to 4104)
    int*      cursor  = ib + 4104;               // 4096
    int*      row_ptr = ib + 8200;               // 4097 (pad to 4104)
    float*    invdeg  = (float*)(ib + 12304);    // 4096
    int*      csr     = ib + 16400;              // E

    Params prm;
    prm.P = P_weight;       prm.bp = model_proj_b;
    prm.b1 = sage1_bl;      prm.b2 = sage2_bl;
    prm.Q = Q_weight;       prm.bt = text_proj_b;
    prm.clsW = cls_W;       prm.clsb = cls_b;
    prm.cWp = model_proj_W; prm.cW1l = sage1_Wl; prm.cW1r = sage1_Wr;
    prm.cW2l = sage2_Wl;    prm.cW2r = sage2_Wr; prm.cWt = text_proj_W;
    prm.srcE = edge_index;  prm.dstE = edge_index + E;
    prm.mids = model_ids;   prm.pids = prompt_ids;
    prm.E = E;              prm.B = B;
    prm.x0f = x0f; prm.h1f = h1f; prm.x2f = x2f;
    prm.invdeg = invdeg;    prm.out = (float*)d_out;
    prm.x0h = x0h; prm.x0l = x0l; prm.h1h = h1h; prm.h1l = h1l;
    prm.agh = agh; prm.agl = agl;
    prm.Wph  = Wh;              prm.Wpl  = Wl;
    prm.W1lh = Wh + nWp;        prm.W1ll = Wl + nWp;
    prm.W1rh = prm.W1lh + nWs;  prm.W1rl = prm.W1ll + nWs;
    prm.W2lh = prm.W1rh + nWs;  prm.W2ll = prm.W1rl + nWs;
    prm.W2rh = prm.W2lh + nWs;  prm.W2rl = prm.W2ll + nWs;
    prm.Wth  = prm.W2rh + nWs;  prm.Wtl  = prm.W2rl + nWs;
    prm.hist = hist; prm.cursor = cursor; prm.row_ptr = row_ptr; prm.csr = csr;
    prm.bar = bar;

    // zero hist + barrier state (one small memset; cursor zeroed in-kernel)
    hipMemsetAsync(hist, 0, 4104 * sizeof(int), stream);

    mega<<<NBLK, NTHR, 0, stream>>>(prm);
}

// Round 9
// 328.832 us; speedup vs baseline: 2.4548x; 2.4548x over previous
//
#include <hip/hip_runtime.h>

#define D0 232
#define MED 1024
#define HID 256
#define TDIM 768
#define NTRAIN 4096
#define NBLK 512
#define NTHR 256
#define TG   384              // graph-team blocks; q team = NBLK-TG = 128
#define QT   (NBLK - TG)
#define FSTRIDE 16            // flag stride in ints (64 B)

typedef short bf16x8 __attribute__((ext_vector_type(8)));
typedef float f32x4  __attribute__((ext_vector_type(4)));
typedef unsigned short u16;

__device__ __forceinline__ u16 f2bf(float f) {
    unsigned u = __float_as_uint(f);
    return (u16)((u + 0x7FFFu + ((u >> 16) & 1u)) >> 16);
}
__device__ __forceinline__ float bf2f(u16 h) {
    return __uint_as_float(((unsigned)h) << 16);
}
__device__ __forceinline__ void cvt8(const float4& a0, const float4& a1,
                                     bf16x8& h, bf16x8& l) {
    float f[8] = {a0.x, a0.y, a0.z, a0.w, a1.x, a1.y, a1.z, a1.w};
    #pragma unroll
    for (int i = 0; i < 8; ++i) {
        u16 hh = f2bf(f[i]);
        h[i] = (short)hh;
        l[i] = (short)f2bf(f[i] - bf2f(hh));
    }
}
__device__ __forceinline__ void cvt4(const float4 v, ushort4& h, ushort4& l) {
    h.x = f2bf(v.x); l.x = f2bf(v.x - bf2f(h.x));
    h.y = f2bf(v.y); l.y = f2bf(v.y - bf2f(h.y));
    h.z = f2bf(v.z); l.z = f2bf(v.z - bf2f(h.z));
    h.w = f2bf(v.w); l.w = f2bf(v.w - bf2f(h.w));
}

#define SROW(r, k) ((((r) ^ (k)) & 7) | ((r) & ~7))

struct Params {
    const float *P, *bp, *b1, *b2, *Q, *bt, *clsW, *clsb;
    const float *cWp, *cW1l, *cW1r, *cW2l, *cW2r, *cWt;
    const int *srcE, *dstE, *mids, *pids;
    int E, B;
    float *x0f, *h1f, *x2f, *qf, *invdeg, *out;
    u16 *x0h, *x0l, *h1h, *h1l, *agh, *agl;
    u16 *Wph, *Wpl, *W1lh, *W1ll, *W1rh, *W1rl, *W2lh, *W2ll, *W2rh, *W2rl, *Wth, *Wtl;
    int *hist, *cursor, *row_ptr, *csr;
    int *flags, *goG, *goT;    // flag array (zeroed each launch) + release cells
};

// ---- contention-free flag barrier: plain stores + read-only polling ----
// Generations are monotonically increasing within a launch; flags/go zeroed
// by the pre-launch memset, so replays are deterministic.
__device__ __forceinline__ void bar_sync(int* flags, int* go, int myIdx, int n,
                                         bool leader, int gen)
{
    __syncthreads();
    if (threadIdx.x == 0) {
        __threadfence();
        __hip_atomic_store(&flags[myIdx * FSTRIDE], gen,
                           __ATOMIC_RELAXED, __HIP_MEMORY_SCOPE_AGENT);
    }
    if (leader) {
        for (int i = threadIdx.x; i < n; i += NTHR) {
            while (__hip_atomic_load(&flags[i * FSTRIDE],
                                     __ATOMIC_RELAXED, __HIP_MEMORY_SCOPE_AGENT) < gen)
                __builtin_amdgcn_s_sleep(2);
        }
        __syncthreads();
        if (threadIdx.x == 0) {
            __threadfence();
            __hip_atomic_store(go, gen, __ATOMIC_RELAXED, __HIP_MEMORY_SCOPE_AGENT);
        }
    }
    if (threadIdx.x == 0) {
        while (__hip_atomic_load(go, __ATOMIC_RELAXED, __HIP_MEMORY_SCOPE_AGENT) < gen)
            __builtin_amdgcn_s_sleep(8);
        __threadfence();
    }
    __syncthreads();
}

// ---- one 32x64 node-GEMM tile (4 waves, wave = 16 cols) ----
template<int CONVA, int RELU, int EMIT, int NPASS>
__device__ __forceinline__ void gemm_tile(
    short* sAh, short* sAl, int row0, int col0,
    const float* A1f, const u16* A1h, const u16* A1l,
    const u16* B1h, const u16* B1l,
    const u16* A2h, const u16* A2l,
    const u16* B2h, const u16* B2l,
    const float* bias,
    float* Cf, u16* Chi, u16* Clo,
    int N, int K)
{
    const int tid  = threadIdx.x;
    const int lane = tid & 63;
    const int wn   = tid >> 6;
    const int l15  = lane & 15;
    const int l4   = lane >> 4;

    const int aRow  = tid >> 3;
    const int aKc   = tid & 7;
    const int aSlot = (aKc * 32 + SROW(aRow, aKc)) * 8;

    const int  colW  = col0 + wn * 16 + l15;
    const bool colOk = colW < N;
    const size_t wBase = (size_t)(colOk ? colW : 0) * K;

    const bf16x8 Z8 = {0, 0, 0, 0, 0, 0, 0, 0};
    f32x4 acc[2];
    acc[0] = (f32x4){0.f, 0.f, 0.f, 0.f};
    acc[1] = (f32x4){0.f, 0.f, 0.f, 0.f};

    for (int pass = 0; pass < NPASS; ++pass) {
        const u16* Bh = pass ? B2h : B1h;
        const u16* Bl = pass ? B2l : B1l;
        const u16* Ah = pass ? A2h : A1h;
        const u16* Al = pass ? A2l : A1l;
        const size_t aOff = (size_t)(row0 + aRow) * K;

        float4 qa0, qa1;
        bf16x8 ph, pl;

        auto loadA = [&](int k0) {
            int gk = k0 + aKc * 8;
            bool v = gk < K;
            if (CONVA && pass == 0) {
                qa0 = v ? *(const float4*)(A1f + aOff + gk)     : make_float4(0.f, 0.f, 0.f, 0.f);
                qa1 = v ? *(const float4*)(A1f + aOff + gk + 4) : make_float4(0.f, 0.f, 0.f, 0.f);
            } else {
                ph = v ? *(const bf16x8*)(Ah + aOff + gk) : Z8;
                pl = v ? *(const bf16x8*)(Al + aOff + gk) : Z8;
            }
        };

        loadA(0);
        for (int k0 = 0; k0 < K; k0 += 64) {
            bf16x8 bh[2], bl[2];
            #pragma unroll
            for (int ks = 0; ks < 2; ++ks) {
                int kb = k0 + (ks * 4 + l4) * 8;
                bool v = colOk && kb < K;
                bh[ks] = v ? *(const bf16x8*)(Bh + wBase + kb) : Z8;
                bl[ks] = v ? *(const bf16x8*)(Bl + wBase + kb) : Z8;
            }
            if (CONVA && pass == 0) {
                bf16x8 h, l; cvt8(qa0, qa1, h, l);
                *(bf16x8*)(sAh + aSlot) = h;
                *(bf16x8*)(sAl + aSlot) = l;
            } else {
                *(bf16x8*)(sAh + aSlot) = ph;
                *(bf16x8*)(sAl + aSlot) = pl;
            }
            __syncthreads();
            if (k0 + 64 < K) loadA(k0 + 64);

            #pragma unroll
            for (int ks = 0; ks < 2; ++ks) {
                const int pb = ks * 4 + l4;
                bf16x8 ah[2], al[2];
                #pragma unroll
                for (int m = 0; m < 2; ++m) {
                    int sl = (pb * 32 + SROW(m * 16 + l15, pb)) * 8;
                    ah[m] = *(const bf16x8*)(sAh + sl);
                    al[m] = *(const bf16x8*)(sAl + sl);
                }
                #pragma unroll
                for (int m = 0; m < 2; ++m)
                    acc[m] = __builtin_amdgcn_mfma_f32_16x16x32_bf16(ah[m], bh[ks], acc[m], 0, 0, 0);
                #pragma unroll
                for (int m = 0; m < 2; ++m)
                    acc[m] = __builtin_amdgcn_mfma_f32_16x16x32_bf16(ah[m], bl[ks], acc[m], 0, 0, 0);
                #pragma unroll
                for (int m = 0; m < 2; ++m)
                    acc[m] = __builtin_amdgcn_mfma_f32_16x16x32_bf16(al[m], bh[ks], acc[m], 0, 0, 0);
            }
            __syncthreads();
        }
    }

    if (colOk) {
        const float bv = bias[colW];
        #pragma unroll
        for (int m = 0; m < 2; ++m) {
            #pragma unroll
            for (int r = 0; r < 4; ++r) {
                int row = row0 + m * 16 + l4 * 4 + r;
                float v = acc[m][r] + bv;
                if (RELU) v = fmaxf(v, 0.0f);
                size_t idx = (size_t)row * N + colW;
                Cf[idx] = v;
                if (EMIT) {
                    u16 h = f2bf(v);
                    Chi[idx] = h;
                    Clo[idx] = f2bf(v - bf2f(h));
                }
            }
        }
    }
}

// ---- one 32-row q-GEMM tile: qf[rows] = Q[pids[rows]] @ Wt^T + bt ----
__device__ __forceinline__ void q_tile(const Params& p, short* sAh, short* sAl, int row0)
{
    constexpr int K = TDIM, N = D0;
    const int tid  = threadIdx.x;
    const int lane = tid & 63;
    const int wn   = tid >> 6;
    const int l15  = lane & 15;
    const int l4   = lane >> 4;

    const int r  = tid >> 3;
    const int kc = tid & 7;
    const int slot = (kc * 32 + SROW(r, kc)) * 8;
    const size_t ab = (size_t)p.pids[row0 + r] * K;

    int colW[4]; bool cOk[4]; size_t wB[4];
    #pragma unroll
    for (int j = 0; j < 4; ++j) {
        colW[j] = wn * 64 + j * 16 + l15;
        cOk[j]  = colW[j] < N;
        wB[j]   = (size_t)(cOk[j] ? colW[j] : 0) * K;
    }

    const bf16x8 Z8 = {0, 0, 0, 0, 0, 0, 0, 0};
    f32x4 acc[2][4];
    #pragma unroll
    for (int m = 0; m < 2; ++m)
        #pragma unroll
        for (int j = 0; j < 4; ++j)
            acc[m][j] = (f32x4){0.f, 0.f, 0.f, 0.f};

    float4 qa0, qa1;
    auto loadA = [&](int k0) {
        qa0 = *(const float4*)(p.Q + ab + k0 + kc * 8);
        qa1 = *(const float4*)(p.Q + ab + k0 + kc * 8 + 4);
    };

    loadA(0);
    for (int k0 = 0; k0 < K; k0 += 64) {
        bf16x8 bh[2][4], bl[2][4];
        #pragma unroll
        for (int ks = 0; ks < 2; ++ks) {
            int kb = k0 + (ks * 4 + l4) * 8;
            #pragma unroll
            for (int j = 0; j < 4; ++j) {
                bh[ks][j] = cOk[j] ? *(const bf16x8*)(p.Wth + wB[j] + kb) : Z8;
                bl[ks][j] = cOk[j] ? *(const bf16x8*)(p.Wtl + wB[j] + kb) : Z8;
            }
        }
        {
            bf16x8 h, l; cvt8(qa0, qa1, h, l);
            *(bf16x8*)(sAh + slot) = h;
            *(bf16x8*)(sAl + slot) = l;
        }
        __syncthreads();
        if (k0 + 64 < K) loadA(k0 + 64);

        #pragma unroll
        for (int ks = 0; ks < 2; ++ks) {
            const int pb = ks * 4 + l4;
            bf16x8 ah[2], al[2];
            #pragma unroll
            for (int m = 0; m < 2; ++m) {
                int sl = (pb * 32 + SROW(m * 16 + l15, pb)) * 8;
                ah[m] = *(const bf16x8*)(sAh + sl);
                al[m] = *(const bf16x8*)(sAl + sl);
            }
            #pragma unroll
            for (int m = 0; m < 2; ++m)
                #pragma unroll
                for (int j = 0; j < 4; ++j)
                    acc[m][j] = __builtin_amdgcn_mfma_f32_16x16x32_bf16(ah[m], bh[ks][j], acc[m][j], 0, 0, 0);
            #pragma unroll
            for (int m = 0; m < 2; ++m)
                #pragma unroll
                for (int j = 0; j < 4; ++j)
                    acc[m][j] = __builtin_amdgcn_mfma_f32_16x16x32_bf16(ah[m], bl[ks][j], acc[m][j], 0, 0, 0);
            #pragma unroll
            for (int m = 0; m < 2; ++m)
                #pragma unroll
                for (int j = 0; j < 4; ++j)
                    acc[m][j] = __builtin_amdgcn_mfma_f32_16x16x32_bf16(al[m], bh[ks][j], acc[m][j], 0, 0, 0);
        }
        __syncthreads();
    }

    #pragma unroll
    for (int j = 0; j < 4; ++j) {
        if (!cOk[j]) continue;
        const float bv = p.bt[colW[j]];
        #pragma unroll
        for (int m = 0; m < 2; ++m)
            #pragma unroll
            for (int r2 = 0; r2 < 4; ++r2) {
                int row = row0 + m * 16 + l4 * 4 + r2;
                p.qf[(size_t)row * N + colW[j]] = acc[m][j][r2] + bv;
            }
    }
}

// ---- aggregation: one wave per node ----
__device__ __forceinline__ void agg_phase(const Params& p, const float* x,
                                          u16* agh, u16* agl, int D)
{
    const int gw   = blockIdx.x * 4 + (threadIdx.x >> 6);
    const int lane = threadIdx.x & 63;
    const bool act = lane < (D >> 2);
    const int fo = lane * 4;

    for (int node = gw; node < NTRAIN; node += TG * 4) {
        const int beg = p.row_ptr[node], end = p.row_ptr[node + 1];
        float4 s0 = {0,0,0,0}, s1 = {0,0,0,0}, s2 = {0,0,0,0}, s3 = {0,0,0,0};
        int j = beg;
        for (; j + 3 < end; j += 4) {
            int n0 = p.csr[j], n1 = p.csr[j+1], n2 = p.csr[j+2], n3 = p.csr[j+3];
            if (act) {
                float4 v0 = *(const float4*)(&x[(size_t)n0 * D + fo]);
                float4 v1 = *(const float4*)(&x[(size_t)n1 * D + fo]);
                float4 v2 = *(const float4*)(&x[(size_t)n2 * D + fo]);
                float4 v3 = *(const float4*)(&x[(size_t)n3 * D + fo]);
                s0.x += v0.x; s0.y += v0.y; s0.z += v0.z; s0.w += v0.w;
                s1.x += v1.x; s1.y += v1.y; s1.z += v1.z; s1.w += v1.w;
                s2.x += v2.x; s2.y += v2.y; s2.z += v2.z; s2.w += v2.w;
                s3.x += v3.x; s3.y += v3.y; s3.z += v3.z; s3.w += v3.w;
            }
        }
        for (; j < end; ++j) {
            int n = p.csr[j];
            if (act) {
                float4 v = *(const float4*)(&x[(size_t)n * D + fo]);
                s0.x += v.x; s0.y += v.y; s0.z += v.z; s0.w += v.w;
            }
        }
        if (act) {
            const float inv = p.invdeg[node];
            float4 rr;
            rr.x = (s0.x + s1.x + s2.x + s3.x) * inv;
            rr.y = (s0.y + s1.y + s2.y + s3.y) * inv;
            rr.z = (s0.z + s1.z + s2.z + s3.z) * inv;
            rr.w = (s0.w + s1.w + s2.w + s3.w) * inv;
            ushort4 h, l; cvt4(rr, h, l);
            *(ushort4*)(&agh[(size_t)node * D + fo]) = h;
            *(ushort4*)(&agl[(size_t)node * D + fo]) = l;
        }
    }
}

// ---- the single persistent kernel ----
__global__ __launch_bounds__(NTHR, 2) void mega(Params p)
{
    __shared__ short sAh[2048], sAl[2048];
    __shared__ int   s_scan[256];

    const int tid  = threadIdx.x;
    const int bid  = blockIdx.x;
    const int gidx = bid * NTHR + tid;
    const bool lead = (bid == 0);

    // ---- P1 (all): edge histogram + weight fp32 -> hi/lo planes ----
    for (int e = gidx; e < p.E; e += NBLK * NTHR)
        atomicAdd(&p.hist[p.dstE[e]], 1);

    auto convseg = [&](const float* s, u16* h, u16* l, int n4) {
        for (int i = gidx; i < n4; i += NBLK * NTHR) {
            float4 v = ((const float4*)s)[i];
            ushort4 hh, ll; cvt4(v, hh, ll);
            ((ushort4*)h)[i] = hh;
            ((ushort4*)l)[i] = ll;
        }
    };
    convseg(p.cWp,  p.Wph,  p.Wpl,  (D0 * MED) / 4);
    convseg(p.cW1l, p.W1lh, p.W1ll, (HID * D0) / 4);
    convseg(p.cW1r, p.W1rh, p.W1rl, (HID * D0) / 4);
    convseg(p.cW2l, p.W2lh, p.W2ll, (HID * D0) / 4);
    convseg(p.cW2r, p.W2rh, p.W2rl, (HID * D0) / 4);
    convseg(p.cWt,  p.Wth,  p.Wtl,  (D0 * TDIM) / 4);
    bar_sync(p.flags, p.goG, bid, NBLK, lead, 1);     // GLOBAL

    if (bid >= TG) {
        // ================= q team: no barriers until the join =================
        for (int t = bid - TG; t < 512; t += QT)
            q_tile(p, sAh, sAl, t * 32);
    } else {
        // ================= graph team =================
        // P2: scan (block 0), invdeg, zero cursors
        if (lead) {
            const int base = tid * 16;
            int v[16]; int s = 0;
            #pragma unroll
            for (int i = 0; i < 16; ++i) { v[i] = p.hist[base + i]; s += v[i]; }
            s_scan[tid] = s;
            __syncthreads();
            for (int off = 1; off < 256; off <<= 1) {
                int t2 = (tid >= off) ? s_scan[tid - off] : 0;
                __syncthreads();
                s_scan[tid] += t2;
                __syncthreads();
            }
            int run = s_scan[tid] - s;
            #pragma unroll
            for (int i = 0; i < 16; ++i) {
                p.row_ptr[base + i] = run;
                p.invdeg[base + i]  = 1.0f / fmaxf((float)v[i], 1.0f);
                p.cursor[base + i]  = 0;
                run += v[i];
            }
            if (tid == 255) p.row_ptr[4096] = p.E;
        }
        bar_sync(p.flags, p.goT, bid, TG, lead, 2);

        // P3: CSR scatter + x0 GEMM
        for (int e = gidx; e < p.E; e += TG * NTHR) {
            int d = p.dstE[e];
            int pos = atomicAdd(&p.cursor[d], 1);
            p.csr[p.row_ptr[d] + pos] = p.srcE[e];
        }
        for (int t = bid; t < 512; t += TG)
            gemm_tile<1, 0, 1, 1>(sAh, sAl, (t >> 2) * 32, (t & 3) * 64,
                p.P, nullptr, nullptr, p.Wph, p.Wpl,
                nullptr, nullptr, nullptr, nullptr,
                p.bp, p.x0f, p.x0h, p.x0l, D0, MED);
        bar_sync(p.flags, p.goT, bid, TG, lead, 3);

        // P4: layer-1 aggregation
        agg_phase(p, p.x0f, p.agh, p.agl, D0);
        bar_sync(p.flags, p.goT, bid, TG, lead, 4);

        // P5: h1 GEMM
        for (int t = bid; t < 512; t += TG)
            gemm_tile<0, 1, 1, 2>(sAh, sAl, (t >> 2) * 32, (t & 3) * 64,
                nullptr, p.agh, p.agl, p.W1lh, p.W1ll,
                p.x0h, p.x0l, p.W1rh, p.W1rl,
                p.b1, p.h1f, p.h1h, p.h1l, HID, D0);
        bar_sync(p.flags, p.goT, bid, TG, lead, 5);

        // P6: layer-2 aggregation
        agg_phase(p, p.h1f, p.agh, p.agl, HID);
        bar_sync(p.flags, p.goT, bid, TG, lead, 6);

        // P7: x2 GEMM
        for (int t = bid; t < 512; t += TG)
            gemm_tile<0, 0, 0, 2>(sAh, sAl, (t >> 2) * 32, (t & 3) * 64,
                nullptr, p.agh, p.agl, p.W2lh, p.W2ll,
                p.h1h, p.h1l, p.W2rh, p.W2rl,
                p.b2, p.x2f, nullptr, nullptr, D0, HID);
    }
    bar_sync(p.flags, p.goG, bid, NBLK, lead, 10);    // GLOBAL join

    // ---- P8 (all): head: out = (qf * x2[mid]) @ clsW^T + clsb ----
    {
        const int lane = tid & 63;
        const int gw   = bid * 4 + (tid >> 6);
        const int d    = lane * 4;
        const bool ok  = d < D0;
        float4 w0 = {0,0,0,0}, w1 = {0,0,0,0};
        if (ok) {
            w0 = *(const float4*)(p.clsW + d);
            w1 = *(const float4*)(p.clsW + D0 + d);
        }
        for (int i = gw; i < p.B; i += NBLK * 4) {
            float s0 = 0.f, s1 = 0.f;
            if (ok) {
                float4 qv = *(const float4*)(p.qf + (size_t)i * D0 + d);
                const float* xr = p.x2f + (size_t)p.mids[i] * D0;
                float4 xv = *(const float4*)(xr + d);
                float p0 = qv.x * xv.x, p1 = qv.y * xv.y, p2 = qv.z * xv.z, p3 = qv.w * xv.w;
                s0 = p0 * w0.x + p1 * w0.y + p2 * w0.z + p3 * w0.w;
                s1 = p0 * w1.x + p1 * w1.y + p2 * w1.z + p3 * w1.w;
            }
            #pragma unroll
            for (int off = 32; off > 0; off >>= 1) {
                s0 += __shfl_down(s0, off);
                s1 += __shfl_down(s1, off);
            }
            if (lane == 0) {
                p.out[(size_t)i * 2 + 0] = s0 + p.clsb[0];
                p.out[(size_t)i * 2 + 1] = s1 + p.clsb[1];
            }
        }
    }
}

extern "C" void kernel_launch(void* const* d_in, const int* in_sizes, int n_in,
                              void* d_out, int out_size, void* d_ws, size_t ws_size,
                              hipStream_t stream)
{
    const float* P_weight     = (const float*)d_in[0];
    const float* model_proj_W = (const float*)d_in[1];
    const float* model_proj_b = (const float*)d_in[2];
    const float* sage1_Wl     = (const float*)d_in[3];
    const float* sage1_bl     = (const float*)d_in[4];
    const float* sage1_Wr     = (const float*)d_in[5];
    const float* sage2_Wl     = (const float*)d_in[6];
    const float* sage2_bl     = (const float*)d_in[7];
    const float* sage2_Wr     = (const float*)d_in[8];
    const float* Q_weight     = (const float*)d_in[9];
    const float* text_proj_W  = (const float*)d_in[10];
    const float* text_proj_b  = (const float*)d_in[11];
    const float* cls_W        = (const float*)d_in[12];
    const float* cls_b        = (const float*)d_in[13];
    const int*   edge_index   = (const int*)d_in[14];
    const int*   model_ids    = (const int*)d_in[15];
    const int*   prompt_ids   = (const int*)d_in[16];

    const int E = in_sizes[14] / 2;
    const int B = in_sizes[15];

    const size_t nX0 = (size_t)NTRAIN * D0;
    const size_t nH1 = (size_t)NTRAIN * HID;
    const size_t nQ  = (size_t)B * D0;
    const size_t nWp = (size_t)D0 * MED;
    const size_t nWs = (size_t)HID * D0;
    const size_t nWt = (size_t)D0 * TDIM;
    const size_t nWAll = nWp + 4 * nWs + nWt;

    float* fb  = (float*)d_ws;
    float* x0f = fb;  fb += nX0;
    float* h1f = fb;  fb += nH1;
    float* x2f = fb;  fb += nX0;
    float* qf  = fb;  fb += nQ;
    u16* sp  = (u16*)fb;
    u16* x0h = sp;    sp += nX0;
    u16* x0l = sp;    sp += nX0;
    u16* h1h = sp;    sp += nH1;
    u16* h1l = sp;    sp += nH1;
    u16* agh = sp;    sp += nH1;
    u16* agl = sp;    sp += nH1;
    u16* Wh  = sp;    sp += nWAll;
    u16* Wl  = sp;    sp += nWAll;
    int* ib  = (int*)sp;
    int*   hist    = ib;                       // [0, 4096)
    int*   flags   = ib + 4096;                // [4096, 12288)  512*16
    int*   goG     = ib + 12288;               // 1 (64B line)
    int*   goT     = ib + 12304;               // 1 (64B line)
    int*   row_ptr = ib + 12320;               // 4097 (pad 4104)
    int*   cursor  = ib + 16424;               // 4096
    float* invdeg  = (float*)(ib + 20520);     // 4096
    int*   csr     = ib + 24616;               // E

    Params prm;
    prm.P = P_weight;       prm.bp = model_proj_b;
    prm.b1 = sage1_bl;      prm.b2 = sage2_bl;
    prm.Q = Q_weight;       prm.bt = text_proj_b;
    prm.clsW = cls_W;       prm.clsb = cls_b;
    prm.cWp = model_proj_W; prm.cW1l = sage1_Wl; prm.cW1r = sage1_Wr;
    prm.cW2l = sage2_Wl;    prm.cW2r = sage2_Wr; prm.cWt = text_proj_W;
    prm.srcE = edge_index;  prm.dstE = edge_index + E;
    prm.mids = model_ids;   prm.pids = prompt_ids;
    prm.E = E;              prm.B = B;
    prm.x0f = x0f; prm.h1f = h1f; prm.x2f = x2f; prm.qf = qf;
    prm.invdeg = invdeg;    prm.out = (float*)d_out;
    prm.x0h = x0h; prm.x0l = x0l; prm.h1h = h1h; prm.h1l = h1l;
    prm.agh = agh; prm.agl = agl;
    prm.Wph  = Wh;              prm.Wpl  = Wl;
    prm.W1lh = Wh + nWp;        prm.W1ll = Wl + nWp;
    prm.W1rh = prm.W1lh + nWs;  prm.W1rl = prm.W1ll + nWs;
    prm.W2lh = prm.W1rh + nWs;  prm.W2ll = prm.W1rl + nWs;
    prm.W2rh = prm.W2lh + nWs;  prm.W2rl = prm.W2ll + nWs;
    prm.Wth  = prm.W2rh + nWs;  prm.Wtl  = prm.W2rl + nWs;
    prm.hist = hist; prm.cursor = cursor; prm.row_ptr = row_ptr; prm.csr = csr;
    prm.flags = flags; prm.goG = goG; prm.goT = goT;

    // zero hist + flags + go cells (one memset; everything else written in-kernel)
    hipMemsetAsync(hist, 0, (size_t)12320 * sizeof(int), stream);

    mega<<<NBLK, NTHR, 0, stream>>>(prm);
}

// Round 10
// 172.227 us; speedup vs baseline: 4.6869x; 1.9093x over previous
//
#include <hip/hip_runtime.h>

#define D0 232
#define MED 1024
#define HID 256
#define TDIM 768
#define NTRAIN 4096

typedef short bf16x8 __attribute__((ext_vector_type(8)));
typedef float f32x4  __attribute__((ext_vector_type(4)));
typedef unsigned short u16;

__device__ __forceinline__ u16 f2bf(float f) {
    unsigned u = __float_as_uint(f);
    return (u16)((u + 0x7FFFu + ((u >> 16) & 1u)) >> 16);
}
__device__ __forceinline__ float bf2f(u16 h) {
    return __uint_as_float(((unsigned)h) << 16);
}
__device__ __forceinline__ void cvt8(const float4& a0, const float4& a1,
                                     bf16x8& h, bf16x8& l) {
    float f[8] = {a0.x, a0.y, a0.z, a0.w, a1.x, a1.y, a1.z, a1.w};
    #pragma unroll
    for (int i = 0; i < 8; ++i) {
        u16 hh = f2bf(f[i]);
        h[i] = (short)hh;
        l[i] = (short)f2bf(f[i] - bf2f(hh));
    }
}
__device__ __forceinline__ void cvt4(const float4 v, ushort4& h, ushort4& l) {
    h.x = f2bf(v.x); l.x = f2bf(v.x - bf2f(h.x));
    h.y = f2bf(v.y); l.y = f2bf(v.y - bf2f(h.y));
    h.z = f2bf(v.z); l.z = f2bf(v.z - bf2f(h.z));
    h.w = f2bf(v.w); l.w = f2bf(v.w - bf2f(h.w));
}

#define SROW(r, k) ((((r) ^ (k)) & 7) | ((r) & ~7))

// ---------------- K1: edge histogram + weight conversion + last-block scan ----------------
struct Seg  { const float* src; u16* hi; u16* lo; int n4; };
struct Segs { Seg s[6]; };

__global__ __launch_bounds__(256) void k1_hist_conv_scan(
    const int* __restrict__ dstE, int* __restrict__ hist, int E,
    Segs segs, int total4,
    int* __restrict__ done, int* __restrict__ row_ptr,
    float* __restrict__ invdeg, int* __restrict__ cursor)
{
    const int tid  = threadIdx.x;
    const int gidx = blockIdx.x * 256 + tid;
    const int gstr = gridDim.x * 256;

    for (int e = gidx; e < E; e += gstr)
        atomicAdd(&hist[dstE[e]], 1);

    for (int i = gidx; i < total4; i += gstr) {
        int k = i, si = 0;
        while (k >= segs.s[si].n4) { k -= segs.s[si].n4; ++si; }
        float4 v = ((const float4*)segs.s[si].src)[k];
        ushort4 h, l; cvt4(v, h, l);
        ((ushort4*)segs.s[si].hi)[k] = h;
        ((ushort4*)segs.s[si].lo)[k] = l;
    }

    // last block to finish performs the 4096-entry scan
    __shared__ int amLast;
    __syncthreads();
    if (tid == 0)
        amLast = (atomicAdd(done, 1) == (int)gridDim.x - 1);
    __syncthreads();
    if (!amLast) return;

    __shared__ int s_scan[256];
    const int base = tid * 16;
    int v[16]; int s = 0;
    #pragma unroll
    for (int i = 0; i < 16; ++i) {
        // hist was written via device-scope atomics (bypassing local L2);
        // read it coherently — a plain load could hit a stale zero line.
        v[i] = __hip_atomic_load(&hist[base + i], __ATOMIC_RELAXED,
                                 __HIP_MEMORY_SCOPE_AGENT);
        s += v[i];
    }
    s_scan[tid] = s;
    __syncthreads();
    for (int off = 1; off < 256; off <<= 1) {
        int t2 = (tid >= off) ? s_scan[tid - off] : 0;
        __syncthreads();
        s_scan[tid] += t2;
        __syncthreads();
    }
    int run = s_scan[tid] - s;
    #pragma unroll
    for (int i = 0; i < 16; ++i) {
        row_ptr[base + i] = run;
        invdeg[base + i]  = 1.0f / fmaxf((float)v[i], 1.0f);
        cursor[base + i]  = 0;
        run += v[i];
    }
    if (tid == 255) row_ptr[4096] = E;
}

// ---------------- node GEMM (optionally fused with CSR scatter) ----------------
// C = A1@B1^T [+ A2@B2^T] + bias. A in LDS (swizzled), B straight from L2.
// Flattened grid: 512 blocks -> (row strip 0..127, col tile 0..3).
template<int SCAT, int CONVA, int RELU, int EMIT, int NPASS>
__global__ __launch_bounds__(256, 2) void gemm_node(
    const int* __restrict__ srcE, const int* __restrict__ dstE,
    const int* __restrict__ row_ptr, int* __restrict__ cursor,
    int* __restrict__ csr, int E,
    const float* __restrict__ A1f,
    const u16* __restrict__ A1h, const u16* __restrict__ A1l,
    const u16* __restrict__ B1h, const u16* __restrict__ B1l,
    const u16* __restrict__ A2h, const u16* __restrict__ A2l,
    const u16* __restrict__ B2h, const u16* __restrict__ B2l,
    const float* __restrict__ bias,
    float* __restrict__ Cf, u16* __restrict__ Chi, u16* __restrict__ Clo,
    int N, int K)
{
    if (SCAT) {
        for (int e = blockIdx.x * 256 + threadIdx.x; e < E; e += gridDim.x * 256) {
            int d = dstE[e];
            int pos = atomicAdd(&cursor[d], 1);
            csr[row_ptr[d] + pos] = srcE[e];
        }
    }

    __shared__ short sAh[2048], sAl[2048];   // 8 panels * 32 rows * 8 shorts

    const int tid  = threadIdx.x;
    const int lane = tid & 63;
    const int wn   = tid >> 6;
    const int l15  = lane & 15;
    const int l4   = lane >> 4;
    const int row0 = (blockIdx.x >> 2) * 32;
    const int col0 = (blockIdx.x & 3) * 64;

    const int aRow  = tid >> 3;
    const int aKc   = tid & 7;
    const int aSlot = (aKc * 32 + SROW(aRow, aKc)) * 8;

    const int  colW  = col0 + wn * 16 + l15;
    const bool colOk = colW < N;
    const size_t wBase = (size_t)(colOk ? colW : 0) * K;

    const bf16x8 Z8 = {0, 0, 0, 0, 0, 0, 0, 0};
    f32x4 acc[2];
    acc[0] = (f32x4){0.f, 0.f, 0.f, 0.f};
    acc[1] = (f32x4){0.f, 0.f, 0.f, 0.f};

    for (int pass = 0; pass < NPASS; ++pass) {
        const u16* Bh = pass ? B2h : B1h;
        const u16* Bl = pass ? B2l : B1l;
        const u16* Ah = pass ? A2h : A1h;
        const u16* Al = pass ? A2l : A1l;
        const size_t aOff = (size_t)(row0 + aRow) * K;

        float4 qa0, qa1;
        bf16x8 ph, pl;

        auto loadA = [&](int k0) {
            int gk = k0 + aKc * 8;
            bool v = gk < K;
            if (CONVA && pass == 0) {
                qa0 = v ? *(const float4*)(A1f + aOff + gk)     : make_float4(0.f, 0.f, 0.f, 0.f);
                qa1 = v ? *(const float4*)(A1f + aOff + gk + 4) : make_float4(0.f, 0.f, 0.f, 0.f);
            } else {
                ph = v ? *(const bf16x8*)(Ah + aOff + gk) : Z8;
                pl = v ? *(const bf16x8*)(Al + aOff + gk) : Z8;
            }
        };

        loadA(0);
        for (int k0 = 0; k0 < K; k0 += 64) {
            bf16x8 bh[2], bl[2];
            #pragma unroll
            for (int ks = 0; ks < 2; ++ks) {
                int kb = k0 + (ks * 4 + l4) * 8;
                bool v = colOk && kb < K;
                bh[ks] = v ? *(const bf16x8*)(Bh + wBase + kb) : Z8;
                bl[ks] = v ? *(const bf16x8*)(Bl + wBase + kb) : Z8;
            }
            if (CONVA && pass == 0) {
                bf16x8 h, l; cvt8(qa0, qa1, h, l);
                *(bf16x8*)(sAh + aSlot) = h;
                *(bf16x8*)(sAl + aSlot) = l;
            } else {
                *(bf16x8*)(sAh + aSlot) = ph;
                *(bf16x8*)(sAl + aSlot) = pl;
            }
            __syncthreads();
            if (k0 + 64 < K) loadA(k0 + 64);

            #pragma unroll
            for (int ks = 0; ks < 2; ++ks) {
                const int pb = ks * 4 + l4;
                bf16x8 ah[2], al[2];
                #pragma unroll
                for (int m = 0; m < 2; ++m) {
                    int sl = (pb * 32 + SROW(m * 16 + l15, pb)) * 8;
                    ah[m] = *(const bf16x8*)(sAh + sl);
                    al[m] = *(const bf16x8*)(sAl + sl);
                }
                #pragma unroll
                for (int m = 0; m < 2; ++m)
                    acc[m] = __builtin_amdgcn_mfma_f32_16x16x32_bf16(ah[m], bh[ks], acc[m], 0, 0, 0);
                #pragma unroll
                for (int m = 0; m < 2; ++m)
                    acc[m] = __builtin_amdgcn_mfma_f32_16x16x32_bf16(ah[m], bl[ks], acc[m], 0, 0, 0);
                #pragma unroll
                for (int m = 0; m < 2; ++m)
                    acc[m] = __builtin_amdgcn_mfma_f32_16x16x32_bf16(al[m], bh[ks], acc[m], 0, 0, 0);
            }
            __syncthreads();
        }
    }

    if (colOk) {
        const float bv = bias[colW];
        #pragma unroll
        for (int m = 0; m < 2; ++m) {
            #pragma unroll
            for (int r = 0; r < 4; ++r) {
                int row = row0 + m * 16 + l4 * 4 + r;
                float v = acc[m][r] + bv;
                if (RELU) v = fmaxf(v, 0.0f);
                size_t idx = (size_t)row * N + colW;
                Cf[idx] = v;
                if (EMIT) {
                    u16 h = f2bf(v);
                    Chi[idx] = h;
                    Clo[idx] = f2bf(v - bf2f(h));
                }
            }
        }
    }
}

// ---------------- aggregation: one wave per node -> bf16 hi/lo planes ----------------
__device__ __forceinline__ void add4(float4& a, const float4 b) {
    a.x += b.x; a.y += b.y; a.z += b.z; a.w += b.w;
}

__global__ __launch_bounds__(256) void node_agg(
    const int* __restrict__ row_ptr, const int* __restrict__ csr,
    const float* __restrict__ invdeg,
    const float* __restrict__ x, u16* __restrict__ agh, u16* __restrict__ agl, int D)
{
    const int wave = threadIdx.x >> 6;
    const int lane = threadIdx.x & 63;
    const int node = blockIdx.x * 4 + wave;
    const int beg = row_ptr[node], end = row_ptr[node + 1];
    const bool act = lane < (D >> 2);
    const int fo = lane * 4;

    float4 s0 = {0,0,0,0}, s1 = {0,0,0,0}, s2 = {0,0,0,0}, s3 = {0,0,0,0};
    int j = beg;
    for (; j + 3 < end; j += 4) {
        int n0 = csr[j], n1 = csr[j+1], n2 = csr[j+2], n3 = csr[j+3];
        if (act) {
            add4(s0, *(const float4*)(&x[(size_t)n0 * D + fo]));
            add4(s1, *(const float4*)(&x[(size_t)n1 * D + fo]));
            add4(s2, *(const float4*)(&x[(size_t)n2 * D + fo]));
            add4(s3, *(const float4*)(&x[(size_t)n3 * D + fo]));
        }
    }
    for (; j < end; ++j) {
        int n = csr[j];
        if (act) add4(s0, *(const float4*)(&x[(size_t)n * D + fo]));
    }
    if (act) {
        const float inv = invdeg[node];
        float4 r;
        r.x = (s0.x + s1.x + s2.x + s3.x) * inv;
        r.y = (s0.y + s1.y + s2.y + s3.y) * inv;
        r.z = (s0.z + s1.z + s2.z + s3.z) * inv;
        r.w = (s0.w + s1.w + s2.w + s3.w) * inv;
        ushort4 h, l; cvt4(r, h, l);
        *(ushort4*)(&agh[(size_t)node * D + fo]) = h;
        *(ushort4*)(&agl[(size_t)node * D + fo]) = l;
    }
}

// ---------------- fused q-GEMM + head: 32-row tiles, 512 blocks, 2 blocks/CU ----------------
__global__ __launch_bounds__(256, 2) void gemm_q_head(
    const float* __restrict__ Q, const int* __restrict__ pids,
    const u16* __restrict__ Wh, const u16* __restrict__ Wl,
    const float* __restrict__ bt,
    const float* __restrict__ x2f, const int* __restrict__ mids,
    const float* __restrict__ clsW, const float* __restrict__ clsb,
    float* __restrict__ out)
{
    constexpr int K = TDIM, N = D0;
    __shared__ short sAh[2048], sAl[2048];
    __shared__ float hacc[64];

    const int tid  = threadIdx.x;
    const int lane = tid & 63;
    const int wn   = tid >> 6;
    const int l15  = lane & 15;
    const int l4   = lane >> 4;
    const int row0 = blockIdx.x * 32;

    const int r  = tid >> 3;
    const int kc = tid & 7;
    const int slot = (kc * 32 + SROW(r, kc)) * 8;
    const size_t ab = (size_t)pids[row0 + r] * K;

    int colW[4]; bool cOk[4]; size_t wB[4];
    #pragma unroll
    for (int j = 0; j < 4; ++j) {
        colW[j] = wn * 64 + j * 16 + l15;
        cOk[j]  = colW[j] < N;
        wB[j]   = (size_t)(cOk[j] ? colW[j] : 0) * K;
    }

    const bf16x8 Z8 = {0, 0, 0, 0, 0, 0, 0, 0};
    f32x4 acc[2][4];
    #pragma unroll
    for (int m = 0; m < 2; ++m)
        #pragma unroll
        for (int j = 0; j < 4; ++j)
            acc[m][j] = (f32x4){0.f, 0.f, 0.f, 0.f};

    float4 qa0, qa1;
    auto loadA = [&](int k0) {
        qa0 = *(const float4*)(Q + ab + k0 + kc * 8);
        qa1 = *(const float4*)(Q + ab + k0 + kc * 8 + 4);
    };

    loadA(0);
    for (int k0 = 0; k0 < K; k0 += 64) {
        bf16x8 bh[2][4], bl[2][4];
        #pragma unroll
        for (int ks = 0; ks < 2; ++ks) {
            int kb = k0 + (ks * 4 + l4) * 8;
            #pragma unroll
            for (int j = 0; j < 4; ++j) {
                bh[ks][j] = cOk[j] ? *(const bf16x8*)(Wh + wB[j] + kb) : Z8;
                bl[ks][j] = cOk[j] ? *(const bf16x8*)(Wl + wB[j] + kb) : Z8;
            }
        }
        {
            bf16x8 h, l; cvt8(qa0, qa1, h, l);
            *(bf16x8*)(sAh + slot) = h;
            *(bf16x8*)(sAl + slot) = l;
        }
        __syncthreads();
        if (k0 + 64 < K) loadA(k0 + 64);

        #pragma unroll
        for (int ks = 0; ks < 2; ++ks) {
            const int pb = ks * 4 + l4;
            bf16x8 ah[2], al[2];
            #pragma unroll
            for (int m = 0; m < 2; ++m) {
                int sl = (pb * 32 + SROW(m * 16 + l15, pb)) * 8;
                ah[m] = *(const bf16x8*)(sAh + sl);
                al[m] = *(const bf16x8*)(sAl + sl);
            }
            #pragma unroll
            for (int m = 0; m < 2; ++m)
                #pragma unroll
                for (int j = 0; j < 4; ++j)
                    acc[m][j] = __builtin_amdgcn_mfma_f32_16x16x32_bf16(ah[m], bh[ks][j], acc[m][j], 0, 0, 0);
            #pragma unroll
            for (int m = 0; m < 2; ++m)
                #pragma unroll
                for (int j = 0; j < 4; ++j)
                    acc[m][j] = __builtin_amdgcn_mfma_f32_16x16x32_bf16(ah[m], bl[ks][j], acc[m][j], 0, 0, 0);
            #pragma unroll
            for (int m = 0; m < 2; ++m)
                #pragma unroll
                for (int j = 0; j < 4; ++j)
                    acc[m][j] = __builtin_amdgcn_mfma_f32_16x16x32_bf16(al[m], bh[ks][j], acc[m][j], 0, 0, 0);
        }
        __syncthreads();
    }

    // ---- fused head: out = ((q + bt) * x2[mid]) @ clsW^T + clsb ----
    if (tid < 64) hacc[tid] = 0.f;
    __syncthreads();

    float bv[4], w0[4], w1[4];
    #pragma unroll
    for (int j = 0; j < 4; ++j) {
        bv[j] = cOk[j] ? bt[colW[j]]       : 0.f;
        w0[j] = cOk[j] ? clsW[colW[j]]     : 0.f;
        w1[j] = cOk[j] ? clsW[N + colW[j]] : 0.f;
    }

    float s0[2][4] = {}, s1[2][4] = {};
    #pragma unroll
    for (int m = 0; m < 2; ++m) {
        #pragma unroll
        for (int rr = 0; rr < 4; ++rr) {
            const int mid = mids[row0 + m * 16 + l4 * 4 + rr];
            const float* xr = x2f + (size_t)mid * N;
            #pragma unroll
            for (int j = 0; j < 4; ++j) {
                if (cOk[j]) {
                    float pv = (acc[m][j][rr] + bv[j]) * xr[colW[j]];
                    s0[m][rr] += pv * w0[j];
                    s1[m][rr] += pv * w1[j];
                }
            }
        }
    }
    #pragma unroll
    for (int off = 1; off < 16; off <<= 1)
        #pragma unroll
        for (int m = 0; m < 2; ++m)
            #pragma unroll
            for (int rr = 0; rr < 4; ++rr) {
                s0[m][rr] += __shfl_xor(s0[m][rr], off);
                s1[m][rr] += __shfl_xor(s1[m][rr], off);
            }
    if (l15 == 0) {
        #pragma unroll
        for (int m = 0; m < 2; ++m)
            #pragma unroll
            for (int rr = 0; rr < 4; ++rr) {
                int lr = m * 16 + l4 * 4 + rr;
                atomicAdd(&hacc[lr * 2 + 0], s0[m][rr]);
                atomicAdd(&hacc[lr * 2 + 1], s1[m][rr]);
            }
    }
    __syncthreads();
    if (tid < 64) {
        int rr = tid >> 1, c = tid & 1;
        out[(size_t)(row0 + rr) * 2 + c] = hacc[tid] + clsb[c];
    }
}

extern "C" void kernel_launch(void* const* d_in, const int* in_sizes, int n_in,
                              void* d_out, int out_size, void* d_ws, size_t ws_size,
                              hipStream_t stream)
{
    const float* P_weight     = (const float*)d_in[0];
    const float* model_proj_W = (const float*)d_in[1];
    const float* model_proj_b = (const float*)d_in[2];
    const float* sage1_Wl     = (const float*)d_in[3];
    const float* sage1_bl     = (const float*)d_in[4];
    const float* sage1_Wr     = (const float*)d_in[5];
    const float* sage2_Wl     = (const float*)d_in[6];
    const float* sage2_bl     = (const float*)d_in[7];
    const float* sage2_Wr     = (const float*)d_in[8];
    const float* Q_weight     = (const float*)d_in[9];
    const float* text_proj_W  = (const float*)d_in[10];
    const float* text_proj_b  = (const float*)d_in[11];
    const float* cls_W        = (const float*)d_in[12];
    const float* cls_b        = (const float*)d_in[13];
    const int*   edge_index   = (const int*)d_in[14];
    const int*   model_ids    = (const int*)d_in[15];
    const int*   prompt_ids   = (const int*)d_in[16];

    const int E = in_sizes[14] / 2;
    const int B = in_sizes[15];
    const int* srcE = edge_index;
    const int* dstE = edge_index + E;

    const size_t nX0 = (size_t)NTRAIN * D0;
    const size_t nH1 = (size_t)NTRAIN * HID;
    const size_t nWp = (size_t)D0 * MED;
    const size_t nWs = (size_t)HID * D0;
    const size_t nWt = (size_t)D0 * TDIM;
    const size_t nWAll = nWp + 4 * nWs + nWt;

    float* fb  = (float*)d_ws;
    float* x0f = fb;  fb += nX0;
    float* h1f = fb;  fb += nH1;
    float* x2f = fb;  fb += nX0;
    u16* sp  = (u16*)fb;
    u16* x0h = sp;    sp += nX0;
    u16* x0l = sp;    sp += nX0;
    u16* h1h = sp;    sp += nH1;
    u16* h1l = sp;    sp += nH1;
    u16* agh = sp;    sp += nH1;
    u16* agl = sp;    sp += nH1;
    u16* Wh  = sp;    sp += nWAll;
    u16* Wl  = sp;    sp += nWAll;
    int* ib  = (int*)sp;
    int*   hist    = ib;                     // 4096
    int*   done    = ib + 4096;              // 1 (pad to 4112)
    int*   row_ptr = ib + 4112;              // 4097 (pad to 4112)
    int*   cursor  = ib + 8224;              // 4096
    float* invdeg  = (float*)(ib + 12320);   // 4096
    int*   csr     = ib + 16416;             // E

    u16 *Wph = Wh,             *Wpl = Wl;
    u16 *W1lh = Wh + nWp,      *W1ll = Wl + nWp;
    u16 *W1rh = W1lh + nWs,    *W1rl = W1ll + nWs;
    u16 *W2lh = W1rh + nWs,    *W2ll = W1rl + nWs;
    u16 *W2rh = W2lh + nWs,    *W2rl = W2ll + nWs;
    u16 *Wth  = W2rh + nWs,    *Wtl  = W2rl + nWs;

    dim3 blk(256);

    // zero hist + done (scan/cursor/row_ptr written in-kernel each launch)
    hipMemsetAsync(hist, 0, 4112 * sizeof(int), stream);

    // K1: histogram + weight planes + last-block scan
    Segs segs;
    segs.s[0] = {model_proj_W, Wph,  Wpl,  (int)(nWp / 4)};
    segs.s[1] = {sage1_Wl,     W1lh, W1ll, (int)(nWs / 4)};
    segs.s[2] = {sage1_Wr,     W1rh, W1rl, (int)(nWs / 4)};
    segs.s[3] = {sage2_Wl,     W2lh, W2ll, (int)(nWs / 4)};
    segs.s[4] = {sage2_Wr,     W2rh, W2rl, (int)(nWs / 4)};
    segs.s[5] = {text_proj_W,  Wth,  Wtl,  (int)(nWt / 4)};
    k1_hist_conv_scan<<<512, blk, 0, stream>>>(
        dstE, hist, E, segs, (int)(nWAll / 4), done, row_ptr, invdeg, cursor);

    // K2: CSR scatter fused with x0 = P @ Wp^T + b (emits planes)
    gemm_node<1, 1, 0, 1, 1><<<512, blk, 0, stream>>>(
        srcE, dstE, row_ptr, cursor, csr, E,
        P_weight, nullptr, nullptr, (const u16*)Wph, (const u16*)Wpl,
        nullptr, nullptr, nullptr, nullptr,
        model_proj_b, x0f, x0h, x0l, D0, MED);

    // K3: layer-1 aggregation -> planes
    node_agg<<<NTRAIN / 4, blk, 0, stream>>>(row_ptr, csr, invdeg, x0f, agh, agl, D0);

    // K4: h1 = relu(agg @ W1l^T + b1 + x0 @ W1r^T) (emits planes)
    gemm_node<0, 0, 1, 1, 2><<<512, blk, 0, stream>>>(
        nullptr, nullptr, nullptr, nullptr, nullptr, 0,
        nullptr, agh, agl, W1lh, W1ll,
        x0h, x0l, W1rh, W1rl,
        sage1_bl, h1f, h1h, h1l, HID, D0);

    // K5: layer-2 aggregation -> planes
    node_agg<<<NTRAIN / 4, blk, 0, stream>>>(row_ptr, csr, invdeg, h1f, agh, agl, HID);

    // K6: x2 = agg @ W2l^T + b2 + h1 @ W2r^T
    gemm_node<0, 0, 0, 0, 2><<<512, blk, 0, stream>>>(
        nullptr, nullptr, nullptr, nullptr, nullptr, 0,
        nullptr, agh, agl, W2lh, W2ll,
        h1h, h1l, W2rh, W2rl,
        sage2_bl, x2f, nullptr, nullptr, D0, HID);

    // K7: fused q-GEMM + head -> d_out
    gemm_q_head<<<B / 32, blk, 0, stream>>>(
        Q_weight, prompt_ids, Wth, Wtl, text_proj_b,
        x2f, model_ids, cls_W, cls_b, (float*)d_out);
}

// Round 12
// 167.713 us; speedup vs baseline: 4.8131x; 1.0269x over previous
//
#include <hip/hip_runtime.h>

#define D0 232
#define MED 1024
#define HID 256
#define TDIM 768
#define NTRAIN 4096

typedef short bf16x8 __attribute__((ext_vector_type(8)));
typedef float f32x4  __attribute__((ext_vector_type(4)));
typedef unsigned short u16;

__device__ __forceinline__ u16 f2bf(float f) {
    unsigned u = __float_as_uint(f);
    return (u16)((u + 0x7FFFu + ((u >> 16) & 1u)) >> 16);
}
__device__ __forceinline__ float bf2f(u16 h) {
    return __uint_as_float(((unsigned)h) << 16);
}
__device__ __forceinline__ void cvt8(const float4& a0, const float4& a1,
                                     bf16x8& h, bf16x8& l) {
    float f[8] = {a0.x, a0.y, a0.z, a0.w, a1.x, a1.y, a1.z, a1.w};
    #pragma unroll
    for (int i = 0; i < 8; ++i) {
        u16 hh = f2bf(f[i]);
        h[i] = (short)hh;
        l[i] = (short)f2bf(f[i] - bf2f(hh));
    }
}
__device__ __forceinline__ void cvt4(const float4 v, ushort4& h, ushort4& l) {
    h.x = f2bf(v.x); l.x = f2bf(v.x - bf2f(h.x));
    h.y = f2bf(v.y); l.y = f2bf(v.y - bf2f(h.y));
    h.z = f2bf(v.z); l.z = f2bf(v.z - bf2f(h.z));
    h.w = f2bf(v.w); l.w = f2bf(v.w - bf2f(h.w));
}

// XOR row swizzle: makes both ds_write_b128 (kc varies per lane-group) and
// ds_read_b128 (row varies per lane) 2-way on 32 banks (free).
#define SROW(r, k) ((((r) ^ (k)) & 7) | ((r) & ~7))

// ---------------- node GEMM: C = A1@W1^T [+ A2@W2^T] + bias ----------------
// A1 fp32 [M][K] (split to bf16 hi/lo in staging); A2/W pre-split planes.
// Tile 32x128, 4 waves (all along N), K-step 64. Direct stores.
template<int RELU, int EMIT>
__global__ __launch_bounds__(256) void gemm_node(
    const float* __restrict__ A1,
    const short* __restrict__ Whi, const short* __restrict__ Wlo,
    const short* __restrict__ A2hi, const short* __restrict__ A2lo,
    const short* __restrict__ W2hi, const short* __restrict__ W2lo,
    const float* __restrict__ bias,
    float* __restrict__ Cf, u16* __restrict__ Chi, u16* __restrict__ Clo,
    int M, int N, int K)
{
    constexpr int TBM = 32, TBN = 128;
    __shared__ short sAh[8 * TBM * 8], sAl[8 * TBM * 8];
    __shared__ short sBh[8 * TBN * 8], sBl[8 * TBN * 8];

    const int tid  = threadIdx.x;
    const int lane = tid & 63;
    const int wn   = tid >> 6;      // wave 0..3, split along N
    const int l15  = lane & 15;
    const int l4   = lane >> 4;
    const int row0 = blockIdx.y * TBM;
    const int col0 = blockIdx.x * TBN;

    const int aRow  = tid >> 3;     // 0..31
    const int aKc   = tid & 7;
    const int aSlot = (aKc * TBM + SROW(aRow, aKc)) * 8;

    int bKcA[4], bSlot[4], bRowL[4];
    #pragma unroll
    for (int i = 0; i < 4; ++i) {
        int cid  = tid * 4 + i;
        bRowL[i] = cid >> 3;        // 0..127
        bKcA[i]  = cid & 7;
        bSlot[i] = (bKcA[i] * TBN + SROW(bRowL[i], bKcA[i])) * 8;
    }

    const bf16x8 Z8 = {0, 0, 0, 0, 0, 0, 0, 0};
    f32x4 acc[2][2];
    #pragma unroll
    for (int m = 0; m < 2; ++m)
        #pragma unroll
        for (int j = 0; j < 2; ++j)
            acc[m][j] = (f32x4){0.f, 0.f, 0.f, 0.f};

    for (int pass = 0; pass < 2; ++pass) {
        if (pass && A2hi == nullptr) break;
        const short* Bh = pass ? W2hi : Whi;
        const short* Bl = pass ? W2lo : Wlo;

        const size_t aBase = (size_t)(row0 + aRow) * K;
        size_t bBase[4]; bool bOk[4];
        #pragma unroll
        for (int i = 0; i < 4; ++i) {
            int c = col0 + bRowL[i];
            bOk[i]   = c < N;
            bBase[i] = (size_t)(bOk[i] ? c : 0) * K;
        }

        float4 a0, a1;
        bf16x8 pAh, pAl, rBh[4], rBl[4];

        auto loadT = [&](int k0) {
            int gk = k0 + aKc * 8;
            bool av = gk < K;              // K % 8 == 0 always
            if (pass == 0) {
                a0 = av ? *reinterpret_cast<const float4*>(A1 + aBase + gk)
                        : make_float4(0.f, 0.f, 0.f, 0.f);
                a1 = av ? *reinterpret_cast<const float4*>(A1 + aBase + gk + 4)
                        : make_float4(0.f, 0.f, 0.f, 0.f);
            } else {
                pAh = av ? *reinterpret_cast<const bf16x8*>(A2hi + aBase + gk) : Z8;
                pAl = av ? *reinterpret_cast<const bf16x8*>(A2lo + aBase + gk) : Z8;
            }
            #pragma unroll
            for (int i = 0; i < 4; ++i) {
                int k = k0 + bKcA[i] * 8;
                bool v = bOk[i] && k < K;
                rBh[i] = v ? *reinterpret_cast<const bf16x8*>(Bh + bBase[i] + k) : Z8;
                rBl[i] = v ? *reinterpret_cast<const bf16x8*>(Bl + bBase[i] + k) : Z8;
            }
        };
        auto storeT = [&]() {
            if (pass == 0) {
                bf16x8 h, l; cvt8(a0, a1, h, l);
                *reinterpret_cast<bf16x8*>(sAh + aSlot) = h;
                *reinterpret_cast<bf16x8*>(sAl + aSlot) = l;
            } else {
                *reinterpret_cast<bf16x8*>(sAh + aSlot) = pAh;
                *reinterpret_cast<bf16x8*>(sAl + aSlot) = pAl;
            }
            #pragma unroll
            for (int i = 0; i < 4; ++i) {
                *reinterpret_cast<bf16x8*>(sBh + bSlot[i]) = rBh[i];
                *reinterpret_cast<bf16x8*>(sBl + bSlot[i]) = rBl[i];
            }
        };

        loadT(0);
        for (int k0 = 0; k0 < K; k0 += 64) {
            storeT();
            __syncthreads();
            if (k0 + 64 < K) loadT(k0 + 64);
            #pragma unroll
            for (int ks = 0; ks < 2; ++ks) {
                const int pb = ks * 4 + l4;
                bf16x8 ah[2], al[2], bh[2], bl[2];
                #pragma unroll
                for (int m = 0; m < 2; ++m) {
                    int r  = m * 16 + l15;
                    int sl = (pb * TBM + SROW(r, pb)) * 8;
                    ah[m] = *reinterpret_cast<const bf16x8*>(sAh + sl);
                    al[m] = *reinterpret_cast<const bf16x8*>(sAl + sl);
                }
                #pragma unroll
                for (int j = 0; j < 2; ++j) {
                    int r  = wn * 32 + j * 16 + l15;
                    int sl = (pb * TBN + SROW(r, pb)) * 8;
                    bh[j] = *reinterpret_cast<const bf16x8*>(sBh + sl);
                    bl[j] = *reinterpret_cast<const bf16x8*>(sBl + sl);
                }
                #pragma unroll
                for (int m = 0; m < 2; ++m)
                    #pragma unroll
                    for (int j = 0; j < 2; ++j)
                        acc[m][j] = __builtin_amdgcn_mfma_f32_16x16x32_bf16(
                            ah[m], bh[j], acc[m][j], 0, 0, 0);
                #pragma unroll
                for (int m = 0; m < 2; ++m)
                    #pragma unroll
                    for (int j = 0; j < 2; ++j)
                        acc[m][j] = __builtin_amdgcn_mfma_f32_16x16x32_bf16(
                            ah[m], bl[j], acc[m][j], 0, 0, 0);
                #pragma unroll
                for (int m = 0; m < 2; ++m)
                    #pragma unroll
                    for (int j = 0; j < 2; ++j)
                        acc[m][j] = __builtin_amdgcn_mfma_f32_16x16x32_bf16(
                            al[m], bh[j], acc[m][j], 0, 0, 0);
            }
            __syncthreads();
        }
    }

    #pragma unroll
    for (int j = 0; j < 2; ++j) {
        int col = col0 + wn * 32 + j * 16 + l15;
        if (col >= N) continue;
        float bv = bias[col];
        #pragma unroll
        for (int m = 0; m < 2; ++m) {
            #pragma unroll
            for (int r = 0; r < 4; ++r) {
                int row = row0 + m * 16 + l4 * 4 + r;
                float v = acc[m][j][r] + bv;
                if (RELU) v = fmaxf(v, 0.0f);
                size_t idx = (size_t)row * N + col;
                Cf[idx] = v;
                if (EMIT) {
                    u16 h = f2bf(v);
                    Chi[idx] = h;
                    Clo[idx] = f2bf(v - bf2f(h));
                }
            }
        }
    }
}

// ------- fused q-GEMM + head: out = (x2[mid] * (Q[pid]@Wt^T + b)) @ clsW^T + cls_b -------
// Tile 64x256 (all of N=232 in one block), 8 waves (2M x 4N), K=768.
__global__ __launch_bounds__(512) void gemm_q_head(
    const float* __restrict__ Q,
    const int* __restrict__ prompt_ids,
    const short* __restrict__ Whi, const short* __restrict__ Wlo,
    const float* __restrict__ bias,
    const float* __restrict__ x2f,
    const int* __restrict__ model_ids,
    const float* __restrict__ cls_W, const float* __restrict__ cls_b,
    float* __restrict__ out)
{
    constexpr int TBM = 64, TBN = 256, K = TDIM, N = D0;
    __shared__ short sAh[8 * TBM * 8], sAl[8 * TBM * 8];
    __shared__ short sBh[8 * TBN * 8], sBl[8 * TBN * 8];
    __shared__ float hacc[TBM][2];

    const int tid  = threadIdx.x;
    const int lane = tid & 63;
    const int wave = tid >> 6;
    const int wm   = wave >> 2;     // 0..1
    const int wn   = wave & 3;      // 0..3
    const int l15  = lane & 15;
    const int l4   = lane >> 4;
    const int row0 = blockIdx.x * TBM;

    const int aRow  = tid >> 3;     // 0..63
    const int aKc   = tid & 7;
    const int aSlot = (aKc * TBM + SROW(aRow, aKc)) * 8;
    const size_t aBase = (size_t)prompt_ids[row0 + aRow] * K;

    int bKcA[4], bSlot[4]; bool bOk[4]; size_t bBase[4];
    #pragma unroll
    for (int i = 0; i < 4; ++i) {
        int cid   = tid * 4 + i;
        int br    = cid >> 3;       // 0..255
        bKcA[i]   = cid & 7;
        bSlot[i]  = (bKcA[i] * TBN + SROW(br, bKcA[i])) * 8;
        bOk[i]    = br < N;
        bBase[i]  = (size_t)(bOk[i] ? br : 0) * K;
    }

    const bf16x8 Z8 = {0, 0, 0, 0, 0, 0, 0, 0};
    f32x4 acc[2][4];
    #pragma unroll
    for (int m = 0; m < 2; ++m)
        #pragma unroll
        for (int j = 0; j < 4; ++j)
            acc[m][j] = (f32x4){0.f, 0.f, 0.f, 0.f};

    float4 a0, a1;
    bf16x8 rBh[4], rBl[4];

    auto loadT = [&](int k0) {
        int gk = k0 + aKc * 8;       // always < K (K%64==0)
        a0 = *reinterpret_cast<const float4*>(Q + aBase + gk);
        a1 = *reinterpret_cast<const float4*>(Q + aBase + gk + 4);
        #pragma unroll
        for (int i = 0; i < 4; ++i) {
            int k = k0 + bKcA[i] * 8;
            rBh[i] = bOk[i] ? *reinterpret_cast<const bf16x8*>(Whi + bBase[i] + k) : Z8;
            rBl[i] = bOk[i] ? *reinterpret_cast<const bf16x8*>(Wlo + bBase[i] + k) : Z8;
        }
    };
    auto storeT = [&]() {
        bf16x8 h, l; cvt8(a0, a1, h, l);
        *reinterpret_cast<bf16x8*>(sAh + aSlot) = h;
        *reinterpret_cast<bf16x8*>(sAl + aSlot) = l;
        #pragma unroll
        for (int i = 0; i < 4; ++i) {
            *reinterpret_cast<bf16x8*>(sBh + bSlot[i]) = rBh[i];
            *reinterpret_cast<bf16x8*>(sBl + bSlot[i]) = rBl[i];
        }
    };

    loadT(0);
    for (int k0 = 0; k0 < K; k0 += 64) {
        storeT();
        __syncthreads();
        if (k0 + 64 < K) loadT(k0 + 64);
        #pragma unroll
        for (int ks = 0; ks < 2; ++ks) {
            const int pb = ks * 4 + l4;
            bf16x8 ah[2], al[2], bh[4], bl[4];
            #pragma unroll
            for (int m = 0; m < 2; ++m) {
                int r  = wm * 32 + m * 16 + l15;
                int sl = (pb * TBM + SROW(r, pb)) * 8;
                ah[m] = *reinterpret_cast<const bf16x8*>(sAh + sl);
                al[m] = *reinterpret_cast<const bf16x8*>(sAl + sl);
            }
            #pragma unroll
            for (int j = 0; j < 4; ++j) {
                int r  = wn * 64 + j * 16 + l15;
                int sl = (pb * TBN + SROW(r, pb)) * 8;
                bh[j] = *reinterpret_cast<const bf16x8*>(sBh + sl);
                bl[j] = *reinterpret_cast<const bf16x8*>(sBl + sl);
            }
            #pragma unroll
            for (int m = 0; m < 2; ++m)
                #pragma unroll
                for (int j = 0; j < 4; ++j)
                    acc[m][j] = __builtin_amdgcn_mfma_f32_16x16x32_bf16(
                        ah[m], bh[j], acc[m][j], 0, 0, 0);
            #pragma unroll
            for (int m = 0; m < 2; ++m)
                #pragma unroll
                for (int j = 0; j < 4; ++j)
                    acc[m][j] = __builtin_amdgcn_mfma_f32_16x16x32_bf16(
                        ah[m], bl[j], acc[m][j], 0, 0, 0);
            #pragma unroll
            for (int m = 0; m < 2; ++m)
                #pragma unroll
                for (int j = 0; j < 4; ++j)
                    acc[m][j] = __builtin_amdgcn_mfma_f32_16x16x32_bf16(
                        al[m], bh[j], acc[m][j], 0, 0, 0);
        }
        __syncthreads();
    }

    // ---- fused head ----
    for (int t = tid; t < TBM * 2; t += 512) ((float*)hacc)[t] = 0.f;
    __syncthreads();

    int mids[2][4];
    #pragma unroll
    for (int m = 0; m < 2; ++m)
        #pragma unroll
        for (int rr = 0; rr < 4; ++rr)
            mids[m][rr] = model_ids[row0 + wm * 32 + m * 16 + l4 * 4 + rr];

    float s[2][4][2] = {};
    #pragma unroll
    for (int j = 0; j < 4; ++j) {
        int col = wn * 64 + j * 16 + l15;
        if (col < N) {
            float w0 = cls_W[col], w1 = cls_W[N + col], bv = bias[col];
            #pragma unroll
            for (int m = 0; m < 2; ++m) {
                #pragma unroll
                for (int rr = 0; rr < 4; ++rr) {
                    float p  = x2f[(size_t)mids[m][rr] * N + col];
                    float pv = (acc[m][j][rr] + bv) * p;
                    s[m][rr][0] += pv * w0;
                    s[m][rr][1] += pv * w1;
                }
            }
        }
    }
    #pragma unroll
    for (int off = 1; off < 16; off <<= 1)
        #pragma unroll
        for (int m = 0; m < 2; ++m)
            #pragma unroll
            for (int rr = 0; rr < 4; ++rr) {
                s[m][rr][0] += __shfl_xor(s[m][rr][0], off);
                s[m][rr][1] += __shfl_xor(s[m][rr][1], off);
            }
    if (l15 == 0) {
        #pragma unroll
        for (int m = 0; m < 2; ++m)
            #pragma unroll
            for (int rr = 0; rr < 4; ++rr) {
                int lr = wm * 32 + m * 16 + l4 * 4 + rr;
                atomicAdd(&hacc[lr][0], s[m][rr][0]);
                atomicAdd(&hacc[lr][1], s[m][rr][1]);
            }
    }
    __syncthreads();
    for (int t = tid; t < TBM; t += 512) {
        out[(size_t)(row0 + t) * 2 + 0] = hacc[t][0] + cls_b[0];
        out[(size_t)(row0 + t) * 2 + 1] = hacc[t][1] + cls_b[1];
    }
}

// ---------------- fp32 -> bf16 hi/lo planes (weights only) ----------------
struct Seg  { const float* src; u16* hi; u16* lo; int n4; };
struct Segs { Seg s[6]; };

__global__ __launch_bounds__(256) void conv_multi(Segs segs, int total4)
{
    int i = blockIdx.x * blockDim.x + threadIdx.x;
    const int stride = gridDim.x * blockDim.x;
    for (; i < total4; i += stride) {
        int k = i, si = 0;
        while (k >= segs.s[si].n4) { k -= segs.s[si].n4; ++si; }
        float4 v = reinterpret_cast<const float4*>(segs.s[si].src)[k];
        float f[4] = {v.x, v.y, v.z, v.w};
        ushort4 h, l;
        u16* hp = (u16*)&h; u16* lp = (u16*)&l;
        #pragma unroll
        for (int c = 0; c < 4; ++c) {
            u16 hh = f2bf(f[c]);
            hp[c] = hh; lp[c] = f2bf(f[c] - bf2f(hh));
        }
        reinterpret_cast<ushort4*>(segs.s[si].hi)[k] = h;
        reinterpret_cast<ushort4*>(segs.s[si].lo)[k] = l;
    }
}

// ---------------- CSR build ----------------
__global__ void hist_kernel(const int* __restrict__ dst, int* __restrict__ hist, int E)
{
    int e = blockIdx.x * blockDim.x + threadIdx.x;
    if (e < E) atomicAdd(&hist[dst[e]], 1);
}

__global__ __launch_bounds__(1024) void scan_kernel(
    const int* __restrict__ hist, int* __restrict__ row_ptr,
    float* __restrict__ invdeg, int E)
{
    __shared__ int s[1024];
    const int t = threadIdx.x;
    int4 c = reinterpret_cast<const int4*>(hist)[t];
    int local = c.x + c.y + c.z + c.w;
    s[t] = local;
    __syncthreads();
    for (int off = 1; off < 1024; off <<= 1) {
        int v = (t >= off) ? s[t - off] : 0;
        __syncthreads();
        s[t] += v;
        __syncthreads();
    }
    int base = s[t] - local;
    row_ptr[4 * t + 0] = base;
    row_ptr[4 * t + 1] = base + c.x;
    row_ptr[4 * t + 2] = base + c.x + c.y;
    row_ptr[4 * t + 3] = base + c.x + c.y + c.z;
    if (t == 1023) row_ptr[4096] = E;
    invdeg[4 * t + 0] = 1.0f / fmaxf((float)c.x, 1.0f);
    invdeg[4 * t + 1] = 1.0f / fmaxf((float)c.y, 1.0f);
    invdeg[4 * t + 2] = 1.0f / fmaxf((float)c.z, 1.0f);
    invdeg[4 * t + 3] = 1.0f / fmaxf((float)c.w, 1.0f);
}

__global__ void scatter_kernel(
    const int* __restrict__ src, const int* __restrict__ dst,
    const int* __restrict__ row_ptr, int* __restrict__ cursor,
    int* __restrict__ csr, int E)
{
    int e = blockIdx.x * blockDim.x + threadIdx.x;
    if (e >= E) return;
    int d = dst[e];
    int pos = atomicAdd(&cursor[d], 1);
    csr[row_ptr[d] + pos] = src[e];
}

__device__ __forceinline__ void add4(float4& a, const float4 b) {
    a.x += b.x; a.y += b.y; a.z += b.z; a.w += b.w;
}

// one wave per node: agg[i] = invdeg[i] * sum_{s in N(i)} x[s]  (fp32 out)
__global__ __launch_bounds__(256) void node_agg(
    const int* __restrict__ row_ptr, const int* __restrict__ csr,
    const float* __restrict__ invdeg,
    const float* __restrict__ x, float* __restrict__ agg, int D)
{
    const int wave = threadIdx.x >> 6;
    const int lane = threadIdx.x & 63;
    const int node = blockIdx.x * 4 + wave;
    const int beg = row_ptr[node], end = row_ptr[node + 1];
    const bool act = lane < (D >> 2);
    const int fo = lane * 4;

    float4 s0 = {0,0,0,0}, s1 = {0,0,0,0}, s2 = {0,0,0,0}, s3 = {0,0,0,0};
    int j = beg;
    for (; j + 3 < end; j += 4) {
        int n0 = csr[j], n1 = csr[j + 1], n2 = csr[j + 2], n3 = csr[j + 3];
        if (act) {
            add4(s0, *(const float4*)(&x[(size_t)n0 * D + fo]));
            add4(s1, *(const float4*)(&x[(size_t)n1 * D + fo]));
            add4(s2, *(const float4*)(&x[(size_t)n2 * D + fo]));
            add4(s3, *(const float4*)(&x[(size_t)n3 * D + fo]));
        }
    }
    for (; j < end; ++j) {
        int n = csr[j];
        if (act) add4(s0, *(const float4*)(&x[(size_t)n * D + fo]));
    }
    if (act) {
        const float inv = invdeg[node];
        float4 r;
        r.x = (s0.x + s1.x + s2.x + s3.x) * inv;
        r.y = (s0.y + s1.y + s2.y + s3.y) * inv;
        r.z = (s0.z + s1.z + s2.z + s3.z) * inv;
        r.w = (s0.w + s1.w + s2.w + s3.w) * inv;
        *reinterpret_cast<float4*>(&agg[(size_t)node * D + fo]) = r;
    }
}

extern "C" void kernel_launch(void* const* d_in, const int* in_sizes, int n_in,
                              void* d_out, int out_size, void* d_ws, size_t ws_size,
                              hipStream_t stream)
{
    const float* P_weight     = (const float*)d_in[0];
    const float* model_proj_W = (const float*)d_in[1];
    const float* model_proj_b = (const float*)d_in[2];
    const float* sage1_Wl     = (const float*)d_in[3];
    const float* sage1_bl     = (const float*)d_in[4];
    const float* sage1_Wr     = (const float*)d_in[5];
    const float* sage2_Wl     = (const float*)d_in[6];
    const float* sage2_bl     = (const float*)d_in[7];
    const float* sage2_Wr     = (const float*)d_in[8];
    const float* Q_weight     = (const float*)d_in[9];
    const float* text_proj_W  = (const float*)d_in[10];
    const float* text_proj_b  = (const float*)d_in[11];
    const float* cls_W        = (const float*)d_in[12];
    const float* cls_b        = (const float*)d_in[13];
    const int*   edge_index   = (const int*)d_in[14];
    const int*   model_ids    = (const int*)d_in[15];
    const int*   prompt_ids   = (const int*)d_in[16];

    const int E = in_sizes[14] / 2;
    const int B = in_sizes[15];
    const int* srcE = edge_index;
    const int* dstE = edge_index + E;

    // ---- workspace layout ----
    const size_t nX0 = (size_t)NTRAIN * D0;   // 950272
    const size_t nH1 = (size_t)NTRAIN * HID;  // 1048576
    const size_t nWp = (size_t)D0 * MED;      // 237568
    const size_t nWs = (size_t)HID * D0;      // 59392 (all four sage weights)
    const size_t nWt = (size_t)D0 * TDIM;     // 178176
    const size_t nWAll = nWp + 4 * nWs + nWt; // 653312

    float* fp  = (float*)d_ws;
    float* x0f = fp;  fp += nX0;
    float* h1f = fp;  fp += nH1;
    float* x2f = fp;  fp += nX0;
    float* agf = fp;  fp += nH1;
    u16* sp  = (u16*)fp;
    u16* x0h = sp;    sp += nX0;
    u16* x0l = sp;    sp += nX0;
    u16* h1h = sp;    sp += nH1;
    u16* h1l = sp;    sp += nH1;
    u16* Wh  = sp;    sp += nWAll;
    u16* Wl  = sp;    sp += nWAll;
    int* ib  = (int*)sp;
    int*   hist    = ib;
    int*   cursor  = ib + 4096;
    int*   row_ptr = ib + 8192;              // 4097, padded
    float* invdeg  = (float*)(ib + 12304);
    int*   csr     = ib + 16400;

    u16 *Wph = Wh,            *Wpl = Wl;
    u16 *W1lh = Wh + nWp,     *W1ll = Wl + nWp;
    u16 *W1rh = W1lh + nWs,   *W1rl = W1ll + nWs;
    u16 *W2lh = W1rh + nWs,   *W2ll = W1rl + nWs;
    u16 *W2rh = W2lh + nWs,   *W2rl = W2ll + nWs;
    u16 *Wth  = W2rh + nWs,   *Wtl  = W2rl + nWs;

    dim3 blk(256);

    hipMemsetAsync(ib, 0, 8192 * sizeof(int), stream);

    // CSR build
    hist_kernel<<<(E + 255) / 256, blk, 0, stream>>>(dstE, hist, E);
    scan_kernel<<<1, 1024, 0, stream>>>(hist, row_ptr, invdeg, E);
    scatter_kernel<<<(E + 255) / 256, blk, 0, stream>>>(srcE, dstE, row_ptr, cursor, csr, E);

    // weights -> hi/lo planes
    Segs segs;
    segs.s[0] = {model_proj_W, Wph,  Wpl,  (int)(nWp / 4)};
    segs.s[1] = {sage1_Wl,     W1lh, W1ll, (int)(nWs / 4)};
    segs.s[2] = {sage1_Wr,     W1rh, W1rl, (int)(nWs / 4)};
    segs.s[3] = {sage2_Wl,     W2lh, W2ll, (int)(nWs / 4)};
    segs.s[4] = {sage2_Wr,     W2rh, W2rl, (int)(nWs / 4)};
    segs.s[5] = {text_proj_W,  Wth,  Wtl,  (int)(nWt / 4)};
    conv_multi<<<640, blk, 0, stream>>>(segs, (int)(nWAll / 4));

    // x0 = P[:4096] @ Wp^T + b    (emits x0 planes)
    gemm_node<0, 1><<<dim3(2, NTRAIN / 32), blk, 0, stream>>>(
        P_weight, (const short*)Wph, (const short*)Wpl,
        nullptr, nullptr, nullptr, nullptr,
        model_proj_b, x0f, x0h, x0l, NTRAIN, D0, MED);

    // layer-1 aggregation
    node_agg<<<NTRAIN / 4, blk, 0, stream>>>(row_ptr, csr, invdeg, x0f, agf, D0);

    // h1 = relu(agg @ W1l^T + b1 + x0 @ W1r^T)   (emits h1 planes)
    gemm_node<1, 1><<<dim3(2, NTRAIN / 32), blk, 0, stream>>>(
        agf, (const short*)W1lh, (const short*)W1ll,
        (const short*)x0h, (const short*)x0l,
        (const short*)W1rh, (const short*)W1rl,
        sage1_bl, h1f, h1h, h1l, NTRAIN, HID, D0);

    // layer-2 aggregation
    node_agg<<<NTRAIN / 4, blk, 0, stream>>>(row_ptr, csr, invdeg, h1f, agf, HID);

    // x2 = agg @ W2l^T + b2 + h1 @ W2r^T
    gemm_node<0, 0><<<dim3(2, NTRAIN / 32), blk, 0, stream>>>(
        agf, (const short*)W2lh, (const short*)W2ll,
        (const short*)h1h, (const short*)h1l,
        (const short*)W2rh, (const short*)W2rl,
        sage2_bl, x2f, nullptr, nullptr, NTRAIN, D0, HID);

    // fused q-GEMM + head -> d_out
    gemm_q_head<<<B / 64, dim3(512), 0, stream>>>(
        Q_weight, prompt_ids, (const short*)Wth, (const short*)Wtl,
        text_proj_b, x2f, model_ids, cls_W, cls_b, (float*)d_out);
}